// Round 2
// baseline (558.283 us; speedup 1.0000x reference)
//
#include <hip/hip_runtime.h>
#include <hip/hip_bf16.h>

typedef __bf16 bf16;
typedef __bf16 bf16x4 __attribute__((ext_vector_type(4)));
typedef __bf16 bf16x8 __attribute__((ext_vector_type(8)));
typedef float  f32x4  __attribute__((ext_vector_type(4)));

#define MFMA16(a,b,c) __builtin_amdgcn_mfma_f32_16x16x32_bf16((a),(b),(c),0,0,0)

// Problem constants: B=32, C=E=512, H=W=32 -> S=1024, 8 heads x 64
constexpr int Cn = 512;
constexpr int Sn = 1024;

// ---------------------------------------------------------------------------
// K0a: x (B,C,S) fp32 -> xbT (B,S,C) bf16   (tiled transpose + convert)
// ---------------------------------------------------------------------------
__global__ __launch_bounds__(256) void k_transpose(const float* __restrict__ x,
                                                   bf16* __restrict__ xbT) {
    int bid = blockIdx.x;            // b*128 + ct*16 + st
    int st = bid & 15;
    int ct = (bid >> 4) & 7;
    int b  = bid >> 7;
    __shared__ bf16 tl[64][72];
    int t  = threadIdx.x;
    int cr = t >> 2;
    int sc = (t & 3) << 4;
    const float4* src4 = (const float4*)(x + ((size_t)b * Cn + ct * 64 + cr) * Sn + st * 64 + sc);
    float4 vbuf[4];
#pragma unroll
    for (int q = 0; q < 4; ++q) vbuf[q] = src4[q];
#pragma unroll
    for (int q = 0; q < 4; ++q) {
        tl[sc + q * 4 + 0][cr] = (bf16)vbuf[q].x;
        tl[sc + q * 4 + 1][cr] = (bf16)vbuf[q].y;
        tl[sc + q * 4 + 2][cr] = (bf16)vbuf[q].z;
        tl[sc + q * 4 + 3][cr] = (bf16)vbuf[q].w;
    }
    __syncthreads();
    int sr = t >> 2;
    int cc = (t & 3) << 4;
    bf16* dst = xbT + ((size_t)b * Sn + st * 64 + sr) * Cn + ct * 64 + cc;
    *(bf16x8*)(dst)     = *(const bf16x8*)&tl[sr][cc];
    *(bf16x8*)(dst + 8) = *(const bf16x8*)&tl[sr][cc + 8];
}

// ---------------------------------------------------------------------------
// K0b: weights fp32 -> bf16, packed [Wq|Wk|Wv|Wo], each 512x512 row-major
// ---------------------------------------------------------------------------
__global__ __launch_bounds__(256) void k_cvt_w(const float* __restrict__ Wq,
                                               const float* __restrict__ Wk,
                                               const float* __restrict__ Wv,
                                               const float* __restrict__ Wo,
                                               bf16* __restrict__ Wb) {
    int tid = blockIdx.x * 256 + threadIdx.x;
    int idx = tid * 8;
    int mat = idx >> 18;
    int off = idx & 262143;
    const float* s = (mat == 0) ? Wq : (mat == 1) ? Wk : (mat == 2) ? Wv : Wo;
    const float4* s4 = (const float4*)(s + off);
    float4 u = s4[0], v = s4[1];
    bf16x8 o;
    o[0] = (bf16)u.x; o[1] = (bf16)u.y; o[2] = (bf16)u.z; o[3] = (bf16)u.w;
    o[4] = (bf16)v.x; o[5] = (bf16)v.y; o[6] = (bf16)v.z; o[7] = (bf16)v.w;
    *(bf16x8*)(Wb + idx) = o;
}

// ---------------------------------------------------------------------------
// K1: fused QKV GEMM + phi + per-block partial KV / ksum.
//     grid = (b, st8) : 256 blocks, each covers 128 s rows (2 sub-tiles of 64).
//     Per sub-tile, per head: one pass over k=512 feeds Q,K,V MFMAs from one
//     shared B-fragment stream (1 ds_read : 3 MFMA). KV accumulated in regs
//     across the block's 128 s, written as bf16 partials [b][h][st8][d][e].
//     phiQ written to global (ALIASES xbT: tile is staged before overwrite).
// ---------------------------------------------------------------------------
__global__ __launch_bounds__(256, 1) void k_qkv(const bf16* __restrict__ xbT,
                                                const bf16* __restrict__ Wb,
                                                bf16* __restrict__ phiQ,
                                                bf16* __restrict__ kvP,
                                                float* __restrict__ ksP) {
    int bid = blockIdx.x;            // b*8 + st8
    int st8 = bid & 7, b = bid >> 3;
    int t = threadIdx.x, lane = t & 63, w = t >> 6, l15 = lane & 15, g = lane >> 4;

    __shared__ bf16 xT[64][520];     // [s][c] tile (66.5 KB)
    __shared__ bf16 pq[64][520];     // phiQ [s][c] full width (66.5 KB)
    __shared__ bf16 pk[64][72];      // phi(K) [d][s] per head
    __shared__ bf16 vv[64][72];      // V      [e][s] per head

    f32x4 kvacc[8][4];
    float ksacc[8][4];
#pragma unroll
    for (int h = 0; h < 8; ++h) {
#pragma unroll
        for (int n = 0; n < 4; ++n) kvacc[h][n] = (f32x4){0.f, 0.f, 0.f, 0.f};
#pragma unroll
        for (int r = 0; r < 4; ++r) ksacc[h][r] = 0.f;
    }

    const bf16* WqB = Wb;
    const bf16* WkB = Wb + 262144;
    const bf16* WvB = Wb + 524288;

    for (int sub = 0; sub < 2; ++sub) {
        int srow0 = st8 * 128 + sub * 64;
        // stage x^T tile [64 s][512 c]
        {
            int sr = t >> 2;
            const bf16* src = xbT + ((size_t)b * Sn + srow0 + sr) * Cn;
#pragma unroll
            for (int it = 0; it < 16; ++it) {
                int c0 = (t & 3) * 8 + it * 32;
                *(bf16x8*)&xT[sr][c0] = *(const bf16x8*)(src + c0);
            }
        }
        __syncthreads();             // A: xT ready (also fences pq bulk-read of prev sub)

#pragma unroll
        for (int h = 0; h < 8; ++h) {
            int arow = h * 64 + w * 16 + l15;
            f32x4 accQ[4], accK[4], accV[4];
#pragma unroll
            for (int n = 0; n < 4; ++n) {
                accQ[n] = (f32x4){0.f,0.f,0.f,0.f};
                accK[n] = (f32x4){0.f,0.f,0.f,0.f};
                accV[n] = (f32x4){0.f,0.f,0.f,0.f};
            }
#pragma unroll
            for (int half = 0; half < 2; ++half) {
                bf16x8 aq[8], ak[8], av[8];
                const bf16* wq0 = WqB + (size_t)arow * 512 + half * 256 + g * 8;
                const bf16* wk0 = WkB + (size_t)arow * 512 + half * 256 + g * 8;
                const bf16* wv0 = WvB + (size_t)arow * 512 + half * 256 + g * 8;
#pragma unroll
                for (int j = 0; j < 8; ++j) {
                    aq[j] = *(const bf16x8*)(wq0 + j * 32);
                    ak[j] = *(const bf16x8*)(wk0 + j * 32);
                    av[j] = *(const bf16x8*)(wv0 + j * 32);
                }
#pragma unroll
                for (int k = 0; k < 8; ++k) {
#pragma unroll
                    for (int n = 0; n < 4; ++n) {
                        bf16x8 bfrag = *(const bf16x8*)&xT[n * 16 + l15][(half * 8 + k) * 32 + g * 8];
                        accQ[n] = MFMA16(aq[k], bfrag, accQ[n]);
                        accK[n] = MFMA16(ak[k], bfrag, accK[n]);
                        accV[n] = MFMA16(av[k], bfrag, accV[n]);
                    }
                }
            }
            __syncthreads();         // B: prev head's KV-MFMA done reading pk/vv
            // phi + writes (C-layout: row d = w*16+g*4+r, col s = n*16+l15)
#pragma unroll
            for (int n = 0; n < 4; ++n) {
                bf16x4 qv;
#pragma unroll
                for (int r = 0; r < 4; ++r) {
                    float kv_ = accK[n][r];
                    kv_ = kv_ > 0.f ? kv_ + 1.f : __expf(kv_);
                    bf16 kb = (bf16)kv_;
                    ksacc[h][r] += (float)kb;
                    pk[w * 16 + g * 4 + r][n * 16 + l15] = kb;
                    vv[w * 16 + g * 4 + r][n * 16 + l15] = (bf16)accV[n][r];
                    float q = accQ[n][r];
                    q = q > 0.f ? q + 1.f : __expf(q);
                    qv[r] = (bf16)q;
                }
                *(bf16x4*)&pq[n * 16 + l15][h * 64 + w * 16 + g * 4] = qv;
            }
            __syncthreads();         // C: pk/vv ready
            // KV += phi(K) @ V^T over this s-tile (k = s, 2 steps)
#pragma unroll
            for (int k2 = 0; k2 < 2; ++k2) {
                bf16x8 afrag = *(const bf16x8*)&pk[w * 16 + l15][k2 * 32 + g * 8];
#pragma unroll
                for (int n = 0; n < 4; ++n) {
                    bf16x8 bfrag = *(const bf16x8*)&vv[n * 16 + l15][k2 * 32 + g * 8];
                    kvacc[h][n] = MFMA16(afrag, bfrag, kvacc[h][n]);
                }
            }
        }
        // bulk coalesced write of phiQ tile (overwrites this block's xbT rows)
        {
            int sr = t >> 2;
            bf16* dst = phiQ + ((size_t)b * Sn + srow0 + sr) * Cn;
#pragma unroll
            for (int it = 0; it < 16; ++it) {
                int c0 = (t & 3) * 8 + it * 32;
                *(bf16x8*)(dst + c0) = *(const bf16x8*)&pq[sr][c0];
            }
        }
    }
    // epilogue: partial KV (bf16, [b][h][st8][d][e]) + partial ksum (fp32)
#pragma unroll
    for (int h = 0; h < 8; ++h) {
        size_t base = ((size_t)((b * 8 + h) * 8 + st8)) * 4096;
#pragma unroll
        for (int n = 0; n < 4; ++n)
#pragma unroll
            for (int r = 0; r < 4; ++r)
                kvP[base + (size_t)(w * 16 + g * 4 + r) * 64 + n * 16 + l15] = (bf16)kvacc[h][n][r];
    }
#pragma unroll
    for (int h = 0; h < 8; ++h)
#pragma unroll
        for (int r = 0; r < 4; ++r) {
            float v = ksacc[h][r];
            v += __shfl_xor(v, 1);
            v += __shfl_xor(v, 2);
            v += __shfl_xor(v, 4);
            v += __shfl_xor(v, 8);
            if (l15 == 0) ksP[((b * 8 + h) * 8 + st8) * 64 + w * 16 + g * 4 + r] = v;
        }
}

// ---------------------------------------------------------------------------
// K2: reduce partials -> KVT[bh][e][d] bf16 (transposed for apply A-frags),
//     ksum[bh][d] fp32.
// ---------------------------------------------------------------------------
__global__ __launch_bounds__(256) void k_red(const bf16* __restrict__ kvP,
                                             const float* __restrict__ ksP,
                                             bf16* __restrict__ KVT,
                                             float* __restrict__ ksum) {
    int bh = blockIdx.x;
    int t = threadIdx.x;
    int d = t >> 2, ec = (t & 3) * 16;
    float acc[16];
#pragma unroll
    for (int i = 0; i < 16; ++i) acc[i] = 0.f;
#pragma unroll
    for (int p = 0; p < 8; ++p) {
        const bf16* src = kvP + ((size_t)bh * 8 + p) * 4096 + d * 64 + ec;
        bf16x8 v0 = *(const bf16x8*)(src);
        bf16x8 v1 = *(const bf16x8*)(src + 8);
#pragma unroll
        for (int i = 0; i < 8; ++i) { acc[i] += (float)v0[i]; acc[8 + i] += (float)v1[i]; }
    }
#pragma unroll
    for (int i = 0; i < 16; ++i)
        KVT[(size_t)bh * 4096 + (ec + i) * 64 + d] = (bf16)acc[i];
    if (t < 64) {
        float s = 0.f;
#pragma unroll
        for (int p = 0; p < 8; ++p) s += ksP[((size_t)bh * 8 + p) * 64 + t];
        ksum[bh * 64 + t] = s;
    }
}

// ---------------------------------------------------------------------------
// K3: apply + output GEMM, per (b, s-tile of 64):
//     denom (all heads, one parallel phase), numerator MFMA per head writing
//     O in-place into the phiQ LDS buffer (disjoint columns), then
//     out = Wo @ O^T + bo  (fp32 coalesced stores).
// ---------------------------------------------------------------------------
__global__ __launch_bounds__(256, 1) void k_apply(const bf16* __restrict__ phiQ,
                                                  const bf16* __restrict__ Wb,
                                                  const bf16* __restrict__ KVT,
                                                  const float* __restrict__ ksum,
                                                  const float* __restrict__ bo,
                                                  float* __restrict__ out) {
    int bid = blockIdx.x;            // b*16 + st
    int st = bid & 15, b = bid >> 4;
    int t = threadIdx.x, lane = t & 63, w = t >> 6, l15 = lane & 15, g = lane >> 4;

    __shared__ bf16 pq[64][520];     // phiQ tile, later reused per-head as O
    __shared__ float ksl[512];
    __shared__ float rden[64][8];
    __shared__ float bol[512];

    {
        int sr = t >> 2;
        const bf16* src = phiQ + ((size_t)b * Sn + st * 64 + sr) * Cn;
#pragma unroll
        for (int it = 0; it < 16; ++it) {
            int c0 = (t & 3) * 8 + it * 32;
            *(bf16x8*)&pq[sr][c0] = *(const bf16x8*)(src + c0);
        }
        ksl[t] = ksum[b * 512 + t];
        ksl[t + 256] = ksum[b * 512 + t + 256];
        bol[t] = bo[t];
        bol[t + 256] = bo[t + 256];
    }
    __syncthreads();
    // denominators: 512 jobs (s,h), 2 per thread
#pragma unroll
    for (int rep = 0; rep < 2; ++rep) {
        int j = rep * 256 + t;
        int s = j & 63, h = j >> 6;
        float acc = 0.f;
#pragma unroll
        for (int dt = 0; dt < 8; ++dt) {
            bf16x8 v = *(const bf16x8*)&pq[s][h * 64 + dt * 8];
#pragma unroll
            for (int i = 0; i < 8; ++i) acc += ksl[h * 64 + dt * 8 + i] * (float)v[i];
        }
        rden[s][h] = 1.f / (acc + 1e-6f);
    }
    __syncthreads();
    // numerator per head; O overwrites pq columns of that head
    for (int h = 0; h < 8; ++h) {
        const bf16* kvb = KVT + ((size_t)(b * 8 + h)) * 4096 + (w * 16 + l15) * 64;
        f32x4 accN[4];
#pragma unroll
        for (int n = 0; n < 4; ++n) accN[n] = (f32x4){0.f,0.f,0.f,0.f};
#pragma unroll
        for (int k2 = 0; k2 < 2; ++k2) {
            bf16x8 afrag = *(const bf16x8*)(kvb + k2 * 32 + g * 8);
#pragma unroll
            for (int n = 0; n < 4; ++n) {
                bf16x8 bfrag = *(const bf16x8*)&pq[n * 16 + l15][h * 64 + k2 * 32 + g * 8];
                accN[n] = MFMA16(afrag, bfrag, accN[n]);
            }
        }
        __syncthreads();             // all reads of pq cols h done before overwrite
#pragma unroll
        for (int n = 0; n < 4; ++n) {
            float rd = rden[n * 16 + l15][h];
            bf16x4 ov;
#pragma unroll
            for (int r = 0; r < 4; ++r) ov[r] = (bf16)(accN[n][r] * rd);
            *(bf16x4*)&pq[n * 16 + l15][h * 64 + w * 16 + g * 4] = ov;
        }
    }
    __syncthreads();
    // out = Wo @ O^T + bo
    const bf16* Wob = Wb + 786432;
    for (int mt = 0; mt < 8; ++mt) {
        int m0 = w * 128 + mt * 16;
        const bf16* wrow = Wob + (size_t)(m0 + l15) * 512;
        f32x4 acc[4];
#pragma unroll
        for (int n = 0; n < 4; ++n) acc[n] = (f32x4){0.f,0.f,0.f,0.f};
#pragma unroll
        for (int k = 0; k < 16; ++k) {
            bf16x8 afrag = *(const bf16x8*)(wrow + k * 32 + g * 8);
#pragma unroll
            for (int n = 0; n < 4; ++n) {
                bf16x8 bfrag = *(const bf16x8*)&pq[n * 16 + l15][k * 32 + g * 8];
                acc[n] = MFMA16(afrag, bfrag, acc[n]);
            }
        }
#pragma unroll
        for (int r = 0; r < 4; ++r) {
            int co = m0 + g * 4 + r;
            float bb = bol[co];
#pragma unroll
            for (int n = 0; n < 4; ++n)
                out[((size_t)b * Cn + co) * Sn + st * 64 + n * 16 + l15] = acc[n][r] + bb;
        }
    }
}

// ---------------------------------------------------------------------------
extern "C" void kernel_launch(void* const* d_in, const int* in_sizes, int n_in,
                              void* d_out, int out_size, void* d_ws, size_t ws_size,
                              hipStream_t stream) {
    const float* x  = (const float*)d_in[0];
    const float* Wq = (const float*)d_in[1];
    const float* Wk = (const float*)d_in[2];
    const float* Wv = (const float*)d_in[3];
    const float* Wo = (const float*)d_in[4];
    const float* bo = (const float*)d_in[5];
    float* out = (float*)d_out;

    char* ws = (char*)d_ws;
    bf16*  xbT  = (bf16*)ws;                       // 33,554,432 B (B*S*C bf16) — later aliased as phiQ
    bf16*  Wb   = (bf16*)(ws + 33554432);          //  2,097,152 B
    bf16*  kvP  = (bf16*)(ws + 35651584);          // 16,777,216 B (32*8*8*64*64 bf16)
    float* ksP  = (float*)(ws + 52428800);         //    524,288 B
    bf16*  KVT  = (bf16*)(ws + 52953088);          //  2,097,152 B
    float* ks   = (float*)(ws + 55050240);         //     65,536 B   (total 55.1 MB)

    k_transpose<<<4096, 256, 0, stream>>>(x, xbT);
    k_cvt_w   <<< 512, 256, 0, stream>>>(Wq, Wk, Wv, Wo, Wb);
    k_qkv     <<< 256, 256, 0, stream>>>(xbT, Wb, xbT /*phiQ alias*/, kvP, ksP);
    k_red     <<< 256, 256, 0, stream>>>(kvP, ksP, KVT, ks);
    k_apply   <<< 512, 256, 0, stream>>>(xbT /*phiQ*/, Wb, KVT, ks, bo, out);
}

// Round 3
// 541.617 us; speedup vs baseline: 1.0308x; 1.0308x over previous
//
#include <hip/hip_runtime.h>
#include <hip/hip_bf16.h>

typedef __bf16 bf16;
typedef __bf16 bf16x4 __attribute__((ext_vector_type(4)));
typedef __bf16 bf16x8 __attribute__((ext_vector_type(8)));
typedef float  f32x4  __attribute__((ext_vector_type(4)));

#define MFMA16(a,b,c) __builtin_amdgcn_mfma_f32_16x16x32_bf16((a),(b),(c),0,0,0)

// Problem constants: B=32, C=E=512, H=W=32 -> S=1024, 8 heads x 64
constexpr int Cn = 512;
constexpr int Sn = 1024;

// ---------------------------------------------------------------------------
// K0a: x (B,C,S) fp32 -> xbT (B,S,C) bf16   (tiled transpose + convert)
// ---------------------------------------------------------------------------
__global__ __launch_bounds__(256) void k_transpose(const float* __restrict__ x,
                                                   bf16* __restrict__ xbT) {
    int bid = blockIdx.x;            // b*128 + ct*16 + st
    int st = bid & 15;
    int ct = (bid >> 4) & 7;
    int b  = bid >> 7;
    __shared__ bf16 tl[64][72];
    int t  = threadIdx.x;
    int cr = t >> 2;
    int sc = (t & 3) << 4;
    const float4* src4 = (const float4*)(x + ((size_t)b * Cn + ct * 64 + cr) * Sn + st * 64 + sc);
    float4 vbuf[4];
#pragma unroll
    for (int q = 0; q < 4; ++q) vbuf[q] = src4[q];
#pragma unroll
    for (int q = 0; q < 4; ++q) {
        tl[sc + q * 4 + 0][cr] = (bf16)vbuf[q].x;
        tl[sc + q * 4 + 1][cr] = (bf16)vbuf[q].y;
        tl[sc + q * 4 + 2][cr] = (bf16)vbuf[q].z;
        tl[sc + q * 4 + 3][cr] = (bf16)vbuf[q].w;
    }
    __syncthreads();
    int sr = t >> 2;
    int cc = (t & 3) << 4;
    bf16* dst = xbT + ((size_t)b * Sn + st * 64 + sr) * Cn + ct * 64 + cc;
    *(bf16x8*)(dst)     = *(const bf16x8*)&tl[sr][cc];
    *(bf16x8*)(dst + 8) = *(const bf16x8*)&tl[sr][cc + 8];
}

// ---------------------------------------------------------------------------
// K0b: weights fp32 -> bf16, packed [Wq|Wk|Wv|Wo], each 512x512 row-major
// ---------------------------------------------------------------------------
__global__ __launch_bounds__(256) void k_cvt_w(const float* __restrict__ Wq,
                                               const float* __restrict__ Wk,
                                               const float* __restrict__ Wv,
                                               const float* __restrict__ Wo,
                                               bf16* __restrict__ Wb) {
    int tid = blockIdx.x * 256 + threadIdx.x;
    int idx = tid * 8;
    int mat = idx >> 18;
    int off = idx & 262143;
    const float* s = (mat == 0) ? Wq : (mat == 1) ? Wk : (mat == 2) ? Wv : Wo;
    const float4* s4 = (const float4*)(s + off);
    float4 u = s4[0], v = s4[1];
    bf16x8 o;
    o[0] = (bf16)u.x; o[1] = (bf16)u.y; o[2] = (bf16)u.z; o[3] = (bf16)u.w;
    o[4] = (bf16)v.x; o[5] = (bf16)v.y; o[6] = (bf16)v.z; o[7] = (bf16)v.w;
    *(bf16x8*)(Wb + idx) = o;
}

// ---------------------------------------------------------------------------
// K1: fused QKV GEMM + phi + per-block partial KV / ksum.  SPILL-FREE version.
//     grid = (b, st8): 256 blocks, 2 sub-tiles of 64 s-rows, all 8 heads.
//     Register diet: KV sub0 partial parked as bf16 (64 VGPR), ksum via
//     lane-group shfl -> LDS (0 VGPR), A-frags chunked 4 k-steps (48 VGPR).
// ---------------------------------------------------------------------------
__global__ __launch_bounds__(256, 1) void k_qkv(const bf16* __restrict__ xbT,
                                                const bf16* __restrict__ Wb,
                                                bf16* __restrict__ phiQ,
                                                bf16* __restrict__ kvP,
                                                float* __restrict__ ksP) {
    int bid = blockIdx.x;            // b*8 + st8
    int st8 = bid & 7, b = bid >> 3;
    int t = threadIdx.x, lane = t & 63, w = t >> 6, l15 = lane & 15, g = lane >> 4;

    __shared__ bf16 xT[64][520];     // 66.5 KB  [s][c] full-k tile
    __shared__ bf16 pq[64][264];     // 33.8 KB  phiQ cols for 4 heads at a time
    __shared__ bf16 pk[64][72];      //  9.2 KB  phi(K) [d][s]
    __shared__ bf16 vv[64][72];      //  9.2 KB  V      [e][s]
    __shared__ float ksl[512];       //  2.0 KB  ksum accumulator [h*64+d]

    ksl[t] = 0.f;
    ksl[t + 256] = 0.f;

    bf16x4 kvbf[8][4];               // sub0 KV partials parked in bf16 (64 VGPR)

    for (int sub = 0; sub < 2; ++sub) {
        int srow0 = st8 * 128 + sub * 64;
        // stage x^T tile [64 s][512 c]
        {
            int sr = t >> 2;
            const bf16* src = xbT + ((size_t)b * Sn + srow0 + sr) * Cn;
#pragma unroll
            for (int it = 0; it < 16; ++it) {
                int c0 = (t & 3) * 8 + it * 32;
                *(bf16x8*)&xT[sr][c0] = *(const bf16x8*)(src + c0);
            }
        }
        __syncthreads();             // A: xT ready (also fences ksl init / pq flush)

#pragma unroll
        for (int h = 0; h < 8; ++h) {
            int arow = h * 64 + w * 16 + l15;
            f32x4 accQ[4], accK[4], accV[4];
#pragma unroll
            for (int n = 0; n < 4; ++n) {
                accQ[n] = (f32x4){0.f,0.f,0.f,0.f};
                accK[n] = (f32x4){0.f,0.f,0.f,0.f};
                accV[n] = (f32x4){0.f,0.f,0.f,0.f};
            }
            // k-loop in 4 chunks of 4 k-steps (A-frags: 48 VGPR live)
#pragma unroll
            for (int kc = 0; kc < 4; ++kc) {
                bf16x8 aq[4], ak[4], av[4];
                const bf16* w0 = Wb + (size_t)arow * 512 + kc * 128 + g * 8;
#pragma unroll
                for (int j = 0; j < 4; ++j) {
                    aq[j] = *(const bf16x8*)(w0 + j * 32);
                    ak[j] = *(const bf16x8*)(w0 + 262144 + j * 32);
                    av[j] = *(const bf16x8*)(w0 + 524288 + j * 32);
                }
#pragma unroll
                for (int k = 0; k < 4; ++k) {
#pragma unroll
                    for (int n = 0; n < 4; ++n) {
                        bf16x8 bfrag = *(const bf16x8*)&xT[n * 16 + l15][(kc * 4 + k) * 32 + g * 8];
                        accQ[n] = MFMA16(aq[k], bfrag, accQ[n]);
                        accK[n] = MFMA16(ak[k], bfrag, accK[n]);
                        accV[n] = MFMA16(av[k], bfrag, accV[n]);
                    }
                }
            }
            __syncthreads();         // B: all waves done with prev head's pk/vv reads
            // phi + writes (C-layout: row d = w*16+g*4+r, col s = n*16+l15)
            float kspart[4] = {0.f, 0.f, 0.f, 0.f};
#pragma unroll
            for (int n = 0; n < 4; ++n) {
                bf16x4 qv;
#pragma unroll
                for (int r = 0; r < 4; ++r) {
                    float kv_ = accK[n][r];
                    kv_ = kv_ > 0.f ? kv_ + 1.f : __expf(kv_);
                    bf16 kb = (bf16)kv_;
                    kspart[r] += (float)kb;
                    pk[w * 16 + g * 4 + r][n * 16 + l15] = kb;
                    vv[w * 16 + g * 4 + r][n * 16 + l15] = (bf16)accV[n][r];
                    float q = accQ[n][r];
                    q = q > 0.f ? q + 1.f : __expf(q);
                    qv[r] = (bf16)q;
                }
                *(bf16x4*)&pq[n * 16 + l15][(h & 3) * 64 + w * 16 + g * 4] = qv;
            }
            // ksum: reduce over the 16-lane group, owner lane accumulates in LDS
#pragma unroll
            for (int r = 0; r < 4; ++r) {
                float v = kspart[r];
                v += __shfl_xor(v, 1);
                v += __shfl_xor(v, 2);
                v += __shfl_xor(v, 4);
                v += __shfl_xor(v, 8);
                if (l15 == 0) ksl[h * 64 + w * 16 + g * 4 + r] += v;
            }
            __syncthreads();         // C: pk/vv (and pq for flush) ready
            // KV accumulate: m=d, n=e, k=s (64 s -> 2 k-steps)
            f32x4 kvacc[4];
#pragma unroll
            for (int n = 0; n < 4; ++n) {
                if (sub == 0) {
                    kvacc[n] = (f32x4){0.f,0.f,0.f,0.f};
                } else {
#pragma unroll
                    for (int r = 0; r < 4; ++r) kvacc[n][r] = (float)kvbf[h][n][r];
                }
            }
#pragma unroll
            for (int k2 = 0; k2 < 2; ++k2) {
                bf16x8 afrag = *(const bf16x8*)&pk[w * 16 + l15][k2 * 32 + g * 8];
#pragma unroll
                for (int n = 0; n < 4; ++n) {
                    bf16x8 bfrag = *(const bf16x8*)&vv[n * 16 + l15][k2 * 32 + g * 8];
                    kvacc[n] = MFMA16(afrag, bfrag, kvacc[n]);
                }
            }
            if (sub == 0) {
#pragma unroll
                for (int n = 0; n < 4; ++n) {
                    bf16x4 p;
#pragma unroll
                    for (int r = 0; r < 4; ++r) p[r] = (bf16)kvacc[n][r];
                    kvbf[h][n] = p;
                }
            } else {
                size_t base = ((size_t)((b * 8 + h) * 8 + st8)) * 4096;
#pragma unroll
                for (int n = 0; n < 4; ++n)
#pragma unroll
                    for (int r = 0; r < 4; ++r)
                        kvP[base + (size_t)(w * 16 + g * 4 + r) * 64 + n * 16 + l15] = (bf16)kvacc[n][r];
            }
            // pq flush: heads 0-3 -> cols [0,256), heads 4-7 -> cols [256,512)
            if (h == 3 || h == 7) {
                int cbase = (h == 3) ? 0 : 256;
                int sr = t >> 2;
                bf16* dst = phiQ + ((size_t)b * Sn + srow0 + sr) * Cn + cbase + (t & 3) * 64;
#pragma unroll
                for (int j = 0; j < 8; ++j)
                    *(bf16x8*)(dst + j * 8) = *(const bf16x8*)&pq[sr][(t & 3) * 64 + j * 8];
            }
        }
    }
    // epilogue: partial ksum -> ksP
    __syncthreads();
#pragma unroll
    for (int rep = 0; rep < 2; ++rep) {
        int idx = rep * 256 + t;
        int h = idx >> 6, d = idx & 63;
        ksP[((b * 8 + h) * 8 + st8) * 64 + d] = ksl[idx];
    }
}

// ---------------------------------------------------------------------------
// K2: reduce partials -> KVT[bh][e][d] bf16 (transposed for apply A-frags),
//     ksum[bh][d] fp32.
// ---------------------------------------------------------------------------
__global__ __launch_bounds__(256) void k_red(const bf16* __restrict__ kvP,
                                             const float* __restrict__ ksP,
                                             bf16* __restrict__ KVT,
                                             float* __restrict__ ksum) {
    int bh = blockIdx.x;
    int t = threadIdx.x;
    int d = t >> 2, ec = (t & 3) * 16;
    float acc[16];
#pragma unroll
    for (int i = 0; i < 16; ++i) acc[i] = 0.f;
#pragma unroll
    for (int p = 0; p < 8; ++p) {
        const bf16* src = kvP + ((size_t)bh * 8 + p) * 4096 + d * 64 + ec;
        bf16x8 v0 = *(const bf16x8*)(src);
        bf16x8 v1 = *(const bf16x8*)(src + 8);
#pragma unroll
        for (int i = 0; i < 8; ++i) { acc[i] += (float)v0[i]; acc[8 + i] += (float)v1[i]; }
    }
#pragma unroll
    for (int i = 0; i < 16; ++i)
        KVT[(size_t)bh * 4096 + (ec + i) * 64 + d] = (bf16)acc[i];
    if (t < 64) {
        float s = 0.f;
#pragma unroll
        for (int p = 0; p < 8; ++p) s += ksP[((size_t)bh * 8 + p) * 64 + t];
        ksum[bh * 64 + t] = s;
    }
}

// ---------------------------------------------------------------------------
// K3: apply + output GEMM, per (b, s-tile of 64):
//     denom (all heads, one parallel phase), numerator MFMA per head writing
//     O in-place into the phiQ LDS buffer (disjoint columns), then
//     out = Wo @ O^T + bo  (fp32 coalesced stores).
// ---------------------------------------------------------------------------
__global__ __launch_bounds__(256, 1) void k_apply(const bf16* __restrict__ phiQ,
                                                  const bf16* __restrict__ Wb,
                                                  const bf16* __restrict__ KVT,
                                                  const float* __restrict__ ksum,
                                                  const float* __restrict__ bo,
                                                  float* __restrict__ out) {
    int bid = blockIdx.x;            // b*16 + st
    int st = bid & 15, b = bid >> 4;
    int t = threadIdx.x, lane = t & 63, w = t >> 6, l15 = lane & 15, g = lane >> 4;

    __shared__ bf16 pq[64][520];     // phiQ tile, later reused per-head as O
    __shared__ float ksl[512];
    __shared__ float rden[64][8];
    __shared__ float bol[512];

    {
        int sr = t >> 2;
        const bf16* src = phiQ + ((size_t)b * Sn + st * 64 + sr) * Cn;
#pragma unroll
        for (int it = 0; it < 16; ++it) {
            int c0 = (t & 3) * 8 + it * 32;
            *(bf16x8*)&pq[sr][c0] = *(const bf16x8*)(src + c0);
        }
        ksl[t] = ksum[b * 512 + t];
        ksl[t + 256] = ksum[b * 512 + t + 256];
        bol[t] = bo[t];
        bol[t + 256] = bo[t + 256];
    }
    __syncthreads();
    // denominators: 512 jobs (s,h), 2 per thread
#pragma unroll
    for (int rep = 0; rep < 2; ++rep) {
        int j = rep * 256 + t;
        int s = j & 63, h = j >> 6;
        float acc = 0.f;
#pragma unroll
        for (int dt = 0; dt < 8; ++dt) {
            bf16x8 v = *(const bf16x8*)&pq[s][h * 64 + dt * 8];
#pragma unroll
            for (int i = 0; i < 8; ++i) acc += ksl[h * 64 + dt * 8 + i] * (float)v[i];
        }
        rden[s][h] = 1.f / (acc + 1e-6f);
    }
    __syncthreads();
    // numerator per head; O overwrites pq columns of that head
    for (int h = 0; h < 8; ++h) {
        const bf16* kvb = KVT + ((size_t)(b * 8 + h)) * 4096 + (w * 16 + l15) * 64;
        f32x4 accN[4];
#pragma unroll
        for (int n = 0; n < 4; ++n) accN[n] = (f32x4){0.f,0.f,0.f,0.f};
#pragma unroll
        for (int k2 = 0; k2 < 2; ++k2) {
            bf16x8 afrag = *(const bf16x8*)(kvb + k2 * 32 + g * 8);
#pragma unroll
            for (int n = 0; n < 4; ++n) {
                bf16x8 bfrag = *(const bf16x8*)&pq[n * 16 + l15][h * 64 + k2 * 32 + g * 8];
                accN[n] = MFMA16(afrag, bfrag, accN[n]);
            }
        }
        __syncthreads();             // all reads of pq cols h done before overwrite
#pragma unroll
        for (int n = 0; n < 4; ++n) {
            float rd = rden[n * 16 + l15][h];
            bf16x4 ov;
#pragma unroll
            for (int r = 0; r < 4; ++r) ov[r] = (bf16)(accN[n][r] * rd);
            *(bf16x4*)&pq[n * 16 + l15][h * 64 + w * 16 + g * 4] = ov;
        }
    }
    __syncthreads();
    // out = Wo @ O^T + bo
    const bf16* Wob = Wb + 786432;
    for (int mt = 0; mt < 8; ++mt) {
        int m0 = w * 128 + mt * 16;
        const bf16* wrow = Wob + (size_t)(m0 + l15) * 512;
        f32x4 acc[4];
#pragma unroll
        for (int n = 0; n < 4; ++n) acc[n] = (f32x4){0.f,0.f,0.f,0.f};
#pragma unroll
        for (int k = 0; k < 16; ++k) {
            bf16x8 afrag = *(const bf16x8*)(wrow + k * 32 + g * 8);
#pragma unroll
            for (int n = 0; n < 4; ++n) {
                bf16x8 bfrag = *(const bf16x8*)&pq[n * 16 + l15][k * 32 + g * 8];
                acc[n] = MFMA16(afrag, bfrag, acc[n]);
            }
        }
#pragma unroll
        for (int r = 0; r < 4; ++r) {
            int co = m0 + g * 4 + r;
            float bb = bol[co];
#pragma unroll
            for (int n = 0; n < 4; ++n)
                out[((size_t)b * Cn + co) * Sn + st * 64 + n * 16 + l15] = acc[n][r] + bb;
        }
    }
}

// ---------------------------------------------------------------------------
extern "C" void kernel_launch(void* const* d_in, const int* in_sizes, int n_in,
                              void* d_out, int out_size, void* d_ws, size_t ws_size,
                              hipStream_t stream) {
    const float* x  = (const float*)d_in[0];
    const float* Wq = (const float*)d_in[1];
    const float* Wk = (const float*)d_in[2];
    const float* Wv = (const float*)d_in[3];
    const float* Wo = (const float*)d_in[4];
    const float* bo = (const float*)d_in[5];
    float* out = (float*)d_out;

    char* ws = (char*)d_ws;
    bf16*  xbT  = (bf16*)ws;                       // 33,554,432 B — aliased as phiQ
    bf16*  Wb   = (bf16*)(ws + 33554432);          //  2,097,152 B
    bf16*  kvP  = (bf16*)(ws + 35651584);          // 16,777,216 B
    float* ksP  = (float*)(ws + 52428800);         //    524,288 B
    bf16*  KVT  = (bf16*)(ws + 52953088);          //  2,097,152 B
    float* ks   = (float*)(ws + 55050240);         //     65,536 B   (total 55.1 MB)

    k_transpose<<<4096, 256, 0, stream>>>(x, xbT);
    k_cvt_w   <<< 512, 256, 0, stream>>>(Wq, Wk, Wv, Wo, Wb);
    k_qkv     <<< 256, 256, 0, stream>>>(xbT, Wb, xbT /*phiQ alias*/, kvP, ksP);
    k_red     <<< 256, 256, 0, stream>>>(kvP, ksP, KVT, ks);
    k_apply   <<< 512, 256, 0, stream>>>(xbT /*phiQ*/, Wb, KVT, ks, bo, out);
}

// Round 4
// 271.940 us; speedup vs baseline: 2.0530x; 1.9917x over previous
//
#include <hip/hip_runtime.h>
#include <hip/hip_bf16.h>

typedef __bf16 bf16;
typedef __bf16 bf16x4 __attribute__((ext_vector_type(4)));
typedef __bf16 bf16x8 __attribute__((ext_vector_type(8)));
typedef float  f32x4  __attribute__((ext_vector_type(4)));

#define MFMA16(a,b,c) __builtin_amdgcn_mfma_f32_16x16x32_bf16((a),(b),(c),0,0,0)

// Problem constants: B=32, C=E=512, H=W=32 -> S=1024, 8 heads x 64
constexpr int Cn = 512;
constexpr int Sn = 1024;

// ---------------------------------------------------------------------------
// K0a: x (B,C,S) fp32 -> xbT (B,S,C) bf16   (tiled transpose + convert)
// ---------------------------------------------------------------------------
__global__ __launch_bounds__(256) void k_transpose(const float* __restrict__ x,
                                                   bf16* __restrict__ xbT) {
    int bid = blockIdx.x;            // b*128 + ct*16 + st
    int st = bid & 15;
    int ct = (bid >> 4) & 7;
    int b  = bid >> 7;
    __shared__ bf16 tl[64][72];
    int t  = threadIdx.x;
    int cr = t >> 2;
    int sc = (t & 3) << 4;
    const float4* src4 = (const float4*)(x + ((size_t)b * Cn + ct * 64 + cr) * Sn + st * 64 + sc);
    float4 vbuf[4];
#pragma unroll
    for (int q = 0; q < 4; ++q) vbuf[q] = src4[q];
#pragma unroll
    for (int q = 0; q < 4; ++q) {
        tl[sc + q * 4 + 0][cr] = (bf16)vbuf[q].x;
        tl[sc + q * 4 + 1][cr] = (bf16)vbuf[q].y;
        tl[sc + q * 4 + 2][cr] = (bf16)vbuf[q].z;
        tl[sc + q * 4 + 3][cr] = (bf16)vbuf[q].w;
    }
    __syncthreads();
    int sr = t >> 2;
    int cc = (t & 3) << 4;
    bf16* dst = xbT + ((size_t)b * Sn + st * 64 + sr) * Cn + ct * 64 + cc;
    *(bf16x8*)(dst)     = *(const bf16x8*)&tl[sr][cc];
    *(bf16x8*)(dst + 8) = *(const bf16x8*)&tl[sr][cc + 8];
}

// ---------------------------------------------------------------------------
// K0b: weights fp32 -> bf16, packed [Wq|Wk|Wv|Wo], each 512x512 row-major
// ---------------------------------------------------------------------------
__global__ __launch_bounds__(256) void k_cvt_w(const float* __restrict__ Wq,
                                               const float* __restrict__ Wk,
                                               const float* __restrict__ Wv,
                                               const float* __restrict__ Wo,
                                               bf16* __restrict__ Wb) {
    int tid = blockIdx.x * 256 + threadIdx.x;
    int idx = tid * 8;
    int mat = idx >> 18;
    int off = idx & 262143;
    const float* s = (mat == 0) ? Wq : (mat == 1) ? Wk : (mat == 2) ? Wv : Wo;
    const float4* s4 = (const float4*)(s + off);
    float4 u = s4[0], v = s4[1];
    bf16x8 o;
    o[0] = (bf16)u.x; o[1] = (bf16)u.y; o[2] = (bf16)u.z; o[3] = (bf16)u.w;
    o[4] = (bf16)v.x; o[5] = (bf16)v.y; o[6] = (bf16)v.z; o[7] = (bf16)v.w;
    *(bf16x8*)(Wb + idx) = o;
}

// ---------------------------------------------------------------------------
// K1: fused QKV GEMM + phi + per-(sub,head) partial KV / ksum.
//     grid = (b, st8): 256 blocks, 2 sub-tiles of 64 s-rows, all 8 heads.
//     h/sub loops are unroll(1) to stop the scheduler hoisting 8 heads of
//     A-frag loads (the R2/R3 spill source). No cross-iteration reg state:
//     KV partials go straight to global (kvP aliases d_out).
// ---------------------------------------------------------------------------
__global__ __launch_bounds__(256, 1) void k_qkv(const bf16* __restrict__ xbT,
                                                const bf16* __restrict__ Wb,
                                                bf16* __restrict__ phiQ,
                                                bf16* __restrict__ kvP,
                                                float* __restrict__ ksP) {
    int bid = blockIdx.x;            // b*8 + st8
    int st8 = bid & 7, b = bid >> 3;
    int t = threadIdx.x, lane = t & 63, w = t >> 6, l15 = lane & 15, g = lane >> 4;

    __shared__ bf16 xT[64][520];     // 66.5 KB  [s][c] full-k tile
    __shared__ bf16 pq[64][264];     // 33.8 KB  phiQ cols for 4 heads at a time
    __shared__ bf16 pk[64][72];      //  9.2 KB  phi(K) [d][s]
    __shared__ bf16 vv[64][72];      //  9.2 KB  V      [e][s]
    __shared__ float ksl[512];       //  2.0 KB  ksum accumulator [h*64+d]

    ksl[t] = 0.f;
    ksl[t + 256] = 0.f;

#pragma unroll 1
    for (int sub = 0; sub < 2; ++sub) {
        int srow0 = st8 * 128 + sub * 64;
        // stage x^T tile [64 s][512 c]
        {
            int sr = t >> 2;
            const bf16* src = xbT + ((size_t)b * Sn + srow0 + sr) * Cn;
#pragma unroll
            for (int it = 0; it < 16; ++it) {
                int c0 = (t & 3) * 8 + it * 32;
                *(bf16x8*)&xT[sr][c0] = *(const bf16x8*)(src + c0);
            }
        }
        __syncthreads();             // A: xT ready (also fences ksl init / pq flush)

#pragma unroll 1
        for (int h = 0; h < 8; ++h) {
            int arow = h * 64 + w * 16 + l15;
            f32x4 accQ[4], accK[4], accV[4];
#pragma unroll
            for (int n = 0; n < 4; ++n) {
                accQ[n] = (f32x4){0.f,0.f,0.f,0.f};
                accK[n] = (f32x4){0.f,0.f,0.f,0.f};
                accV[n] = (f32x4){0.f,0.f,0.f,0.f};
            }
            // k-loop: 4 chunks of 4 k-steps; unroll 2 bounds frag liveness
#pragma unroll 2
            for (int kc = 0; kc < 4; ++kc) {
                bf16x8 aq[4], ak[4], av[4];
                const bf16* w0 = Wb + (size_t)arow * 512 + kc * 128 + g * 8;
#pragma unroll
                for (int j = 0; j < 4; ++j) {
                    aq[j] = *(const bf16x8*)(w0 + j * 32);
                    ak[j] = *(const bf16x8*)(w0 + 262144 + j * 32);
                    av[j] = *(const bf16x8*)(w0 + 524288 + j * 32);
                }
#pragma unroll
                for (int k = 0; k < 4; ++k) {
#pragma unroll
                    for (int n = 0; n < 4; ++n) {
                        bf16x8 bfrag = *(const bf16x8*)&xT[n * 16 + l15][(kc * 4 + k) * 32 + g * 8];
                        accQ[n] = MFMA16(aq[k], bfrag, accQ[n]);
                        accK[n] = MFMA16(ak[k], bfrag, accK[n]);
                        accV[n] = MFMA16(av[k], bfrag, accV[n]);
                    }
                }
            }
            __syncthreads();         // B: all waves done with prev head's pk/vv reads
            // phi + writes (C-layout: row d = w*16+g*4+r, col s = n*16+l15)
            float kspart[4] = {0.f, 0.f, 0.f, 0.f};
#pragma unroll
            for (int n = 0; n < 4; ++n) {
                bf16x4 qv;
#pragma unroll
                for (int r = 0; r < 4; ++r) {
                    float kv_ = accK[n][r];
                    kv_ = kv_ > 0.f ? kv_ + 1.f : __expf(kv_);
                    bf16 kb = (bf16)kv_;
                    kspart[r] += (float)kb;
                    pk[w * 16 + g * 4 + r][n * 16 + l15] = kb;
                    vv[w * 16 + g * 4 + r][n * 16 + l15] = (bf16)accV[n][r];
                    float q = accQ[n][r];
                    q = q > 0.f ? q + 1.f : __expf(q);
                    qv[r] = (bf16)q;
                }
                *(bf16x4*)&pq[n * 16 + l15][(h & 3) * 64 + w * 16 + g * 4] = qv;
            }
            // ksum: reduce over the 16-lane group, owner lane accumulates in LDS
#pragma unroll
            for (int r = 0; r < 4; ++r) {
                float v = kspart[r];
                v += __shfl_xor(v, 1);
                v += __shfl_xor(v, 2);
                v += __shfl_xor(v, 4);
                v += __shfl_xor(v, 8);
                if (l15 == 0) ksl[h * 64 + w * 16 + g * 4 + r] += v;
            }
            __syncthreads();         // C: pk/vv (and pq for flush) ready
            // KV partial: m=d, n=e, k=s (64 s -> 2 k-steps), straight to global
            f32x4 kvacc[4];
#pragma unroll
            for (int n = 0; n < 4; ++n) kvacc[n] = (f32x4){0.f,0.f,0.f,0.f};
#pragma unroll
            for (int k2 = 0; k2 < 2; ++k2) {
                bf16x8 afrag = *(const bf16x8*)&pk[w * 16 + l15][k2 * 32 + g * 8];
#pragma unroll
                for (int n = 0; n < 4; ++n) {
                    bf16x8 bfrag = *(const bf16x8*)&vv[n * 16 + l15][k2 * 32 + g * 8];
                    kvacc[n] = MFMA16(afrag, bfrag, kvacc[n]);
                }
            }
            {
                size_t base = ((size_t)((b * 8 + h) * 16 + st8 * 2 + sub)) * 4096;
#pragma unroll
                for (int n = 0; n < 4; ++n)
#pragma unroll
                    for (int r = 0; r < 4; ++r)
                        kvP[base + (size_t)(w * 16 + g * 4 + r) * 64 + n * 16 + l15] = (bf16)kvacc[n][r];
            }
            // pq flush: heads 0-3 -> cols [0,256), heads 4-7 -> cols [256,512)
            if (h == 3 || h == 7) {
                int cbase = (h == 3) ? 0 : 256;
                int sr = t >> 2;
                bf16* dst = phiQ + ((size_t)b * Sn + srow0 + sr) * Cn + cbase + (t & 3) * 64;
#pragma unroll
                for (int j = 0; j < 8; ++j)
                    *(bf16x8*)(dst + j * 8) = *(const bf16x8*)&pq[sr][(t & 3) * 64 + j * 8];
            }
        }
    }
    // epilogue: partial ksum -> ksP
    __syncthreads();
#pragma unroll
    for (int rep = 0; rep < 2; ++rep) {
        int idx = rep * 256 + t;
        int h = idx >> 6, d = idx & 63;
        ksP[((b * 8 + h) * 8 + st8) * 64 + d] = ksl[idx];
    }
}

// ---------------------------------------------------------------------------
// K2: reduce partials -> KVT[bh][e][d] bf16 (transposed for apply A-frags),
//     ksum[bh][d] fp32.
// ---------------------------------------------------------------------------
__global__ __launch_bounds__(256) void k_red(const bf16* __restrict__ kvP,
                                             const float* __restrict__ ksP,
                                             bf16* __restrict__ KVT,
                                             float* __restrict__ ksum) {
    int bh = blockIdx.x;
    int t = threadIdx.x;
    int d = t >> 2, ec = (t & 3) * 16;
    float acc[16];
#pragma unroll
    for (int i = 0; i < 16; ++i) acc[i] = 0.f;
#pragma unroll
    for (int p = 0; p < 16; ++p) {
        const bf16* src = kvP + ((size_t)bh * 16 + p) * 4096 + d * 64 + ec;
        bf16x8 v0 = *(const bf16x8*)(src);
        bf16x8 v1 = *(const bf16x8*)(src + 8);
#pragma unroll
        for (int i = 0; i < 8; ++i) { acc[i] += (float)v0[i]; acc[8 + i] += (float)v1[i]; }
    }
#pragma unroll
    for (int i = 0; i < 16; ++i)
        KVT[(size_t)bh * 4096 + (ec + i) * 64 + d] = (bf16)acc[i];
    if (t < 64) {
        float s = 0.f;
#pragma unroll
        for (int p = 0; p < 8; ++p) s += ksP[((size_t)bh * 8 + p) * 64 + t];
        ksum[bh * 64 + t] = s;
    }
}

// ---------------------------------------------------------------------------
// K3: apply + output GEMM, per (b, s-tile of 64):
//     denom (all heads, one parallel phase), numerator MFMA per head writing
//     O in-place into the phiQ LDS buffer (disjoint columns), then
//     out = Wo @ O^T + bo  (fp32 coalesced stores).
// ---------------------------------------------------------------------------
__global__ __launch_bounds__(256, 1) void k_apply(const bf16* __restrict__ phiQ,
                                                  const bf16* __restrict__ Wb,
                                                  const bf16* __restrict__ KVT,
                                                  const float* __restrict__ ksum,
                                                  const float* __restrict__ bo,
                                                  float* __restrict__ out) {
    int bid = blockIdx.x;            // b*16 + st
    int st = bid & 15, b = bid >> 4;
    int t = threadIdx.x, lane = t & 63, w = t >> 6, l15 = lane & 15, g = lane >> 4;

    __shared__ bf16 pq[64][520];     // phiQ tile, later reused per-head as O
    __shared__ float ksl[512];
    __shared__ float rden[64][8];
    __shared__ float bol[512];

    {
        int sr = t >> 2;
        const bf16* src = phiQ + ((size_t)b * Sn + st * 64 + sr) * Cn;
#pragma unroll
        for (int it = 0; it < 16; ++it) {
            int c0 = (t & 3) * 8 + it * 32;
            *(bf16x8*)&pq[sr][c0] = *(const bf16x8*)(src + c0);
        }
        ksl[t] = ksum[b * 512 + t];
        ksl[t + 256] = ksum[b * 512 + t + 256];
        bol[t] = bo[t];
        bol[t + 256] = bo[t + 256];
    }
    __syncthreads();
    // denominators: 512 jobs (s,h), 2 per thread
#pragma unroll
    for (int rep = 0; rep < 2; ++rep) {
        int j = rep * 256 + t;
        int s = j & 63, h = j >> 6;
        float acc = 0.f;
#pragma unroll
        for (int dt = 0; dt < 8; ++dt) {
            bf16x8 v = *(const bf16x8*)&pq[s][h * 64 + dt * 8];
#pragma unroll
            for (int i = 0; i < 8; ++i) acc += ksl[h * 64 + dt * 8 + i] * (float)v[i];
        }
        rden[s][h] = 1.f / (acc + 1e-6f);
    }
    __syncthreads();
    // numerator per head; O overwrites pq columns of that head
    for (int h = 0; h < 8; ++h) {
        const bf16* kvb = KVT + ((size_t)(b * 8 + h)) * 4096 + (w * 16 + l15) * 64;
        f32x4 accN[4];
#pragma unroll
        for (int n = 0; n < 4; ++n) accN[n] = (f32x4){0.f,0.f,0.f,0.f};
#pragma unroll
        for (int k2 = 0; k2 < 2; ++k2) {
            bf16x8 afrag = *(const bf16x8*)(kvb + k2 * 32 + g * 8);
#pragma unroll
            for (int n = 0; n < 4; ++n) {
                bf16x8 bfrag = *(const bf16x8*)&pq[n * 16 + l15][h * 64 + k2 * 32 + g * 8];
                accN[n] = MFMA16(afrag, bfrag, accN[n]);
            }
        }
        __syncthreads();             // all reads of pq cols h done before overwrite
#pragma unroll
        for (int n = 0; n < 4; ++n) {
            float rd = rden[n * 16 + l15][h];
            bf16x4 ov;
#pragma unroll
            for (int r = 0; r < 4; ++r) ov[r] = (bf16)(accN[n][r] * rd);
            *(bf16x4*)&pq[n * 16 + l15][h * 64 + w * 16 + g * 4] = ov;
        }
    }
    __syncthreads();
    // out = Wo @ O^T + bo
    const bf16* Wob = Wb + 786432;
    for (int mt = 0; mt < 8; ++mt) {
        int m0 = w * 128 + mt * 16;
        const bf16* wrow = Wob + (size_t)(m0 + l15) * 512;
        f32x4 acc[4];
#pragma unroll
        for (int n = 0; n < 4; ++n) acc[n] = (f32x4){0.f,0.f,0.f,0.f};
#pragma unroll
        for (int k = 0; k < 16; ++k) {
            bf16x8 afrag = *(const bf16x8*)(wrow + k * 32 + g * 8);
#pragma unroll
            for (int n = 0; n < 4; ++n) {
                bf16x8 bfrag = *(const bf16x8*)&pq[n * 16 + l15][k * 32 + g * 8];
                acc[n] = MFMA16(afrag, bfrag, acc[n]);
            }
        }
#pragma unroll
        for (int r = 0; r < 4; ++r) {
            int co = m0 + g * 4 + r;
            float bb = bol[co];
#pragma unroll
            for (int n = 0; n < 4; ++n)
                out[((size_t)b * Cn + co) * Sn + st * 64 + n * 16 + l15] = acc[n][r] + bb;
        }
    }
}

// ---------------------------------------------------------------------------
extern "C" void kernel_launch(void* const* d_in, const int* in_sizes, int n_in,
                              void* d_out, int out_size, void* d_ws, size_t ws_size,
                              hipStream_t stream) {
    const float* x  = (const float*)d_in[0];
    const float* Wq = (const float*)d_in[1];
    const float* Wk = (const float*)d_in[2];
    const float* Wv = (const float*)d_in[3];
    const float* Wo = (const float*)d_in[4];
    const float* bo = (const float*)d_in[5];
    float* out = (float*)d_out;

    char* ws = (char*)d_ws;
    bf16*  xbT  = (bf16*)ws;                       // 33,554,432 B — aliased as phiQ
    bf16*  Wb   = (bf16*)(ws + 33554432);          //  2,097,152 B
    float* ksP  = (float*)(ws + 35651584);         //    524,288 B
    bf16*  KVT  = (bf16*)(ws + 36175872);          //  2,097,152 B
    float* ks   = (float*)(ws + 38273024);         //     65,536 B   (total 38.3 MB)

    // KV partials (32 MB) alias d_out: fully written by k_qkv, consumed by
    // k_red, then k_apply overwrites the whole output buffer.
    bf16*  kvP  = (bf16*)d_out;

    k_transpose<<<4096, 256, 0, stream>>>(x, xbT);
    k_cvt_w   <<< 512, 256, 0, stream>>>(Wq, Wk, Wv, Wo, Wb);
    k_qkv     <<< 256, 256, 0, stream>>>(xbT, Wb, xbT /*phiQ alias*/, kvP, ksP);
    k_red     <<< 256, 256, 0, stream>>>(kvP, ksP, KVT, ks);
    k_apply   <<< 512, 256, 0, stream>>>(xbT /*phiQ*/, Wb, KVT, ks, bo, out);
}

// Round 5
// 232.112 us; speedup vs baseline: 2.4052x; 1.1716x over previous
//
#include <hip/hip_runtime.h>
#include <hip/hip_bf16.h>

typedef __bf16 bf16;
typedef __bf16 bf16x4 __attribute__((ext_vector_type(4)));
typedef __bf16 bf16x8 __attribute__((ext_vector_type(8)));
typedef float  f32x4  __attribute__((ext_vector_type(4)));

#define MFMA16(a,b,c) __builtin_amdgcn_mfma_f32_16x16x32_bf16((a),(b),(c),0,0,0)

// Problem constants: B=32, C=E=512, H=W=32 -> S=1024, 8 heads x 64
constexpr int Cn = 512;
constexpr int Sn = 1024;

// ---------------------------------------------------------------------------
// K0a: x (B,C,S) fp32 -> xbT (B,S,C) bf16   (tiled transpose + convert)
// ---------------------------------------------------------------------------
__global__ __launch_bounds__(256) void k_transpose(const float* __restrict__ x,
                                                   bf16* __restrict__ xbT) {
    int bid = blockIdx.x;            // b*128 + ct*16 + st
    int st = bid & 15;
    int ct = (bid >> 4) & 7;
    int b  = bid >> 7;
    __shared__ bf16 tl[64][72];
    int t  = threadIdx.x;
    int cr = t >> 2;
    int sc = (t & 3) << 4;
    const float4* src4 = (const float4*)(x + ((size_t)b * Cn + ct * 64 + cr) * Sn + st * 64 + sc);
    float4 vbuf[4];
#pragma unroll
    for (int q = 0; q < 4; ++q) vbuf[q] = src4[q];
#pragma unroll
    for (int q = 0; q < 4; ++q) {
        tl[sc + q * 4 + 0][cr] = (bf16)vbuf[q].x;
        tl[sc + q * 4 + 1][cr] = (bf16)vbuf[q].y;
        tl[sc + q * 4 + 2][cr] = (bf16)vbuf[q].z;
        tl[sc + q * 4 + 3][cr] = (bf16)vbuf[q].w;
    }
    __syncthreads();
    int sr = t >> 2;
    int cc = (t & 3) << 4;
    bf16* dst = xbT + ((size_t)b * Sn + st * 64 + sr) * Cn + ct * 64 + cc;
    *(bf16x8*)(dst)     = *(const bf16x8*)&tl[sr][cc];
    *(bf16x8*)(dst + 8) = *(const bf16x8*)&tl[sr][cc + 8];
}

// ---------------------------------------------------------------------------
// K0b: weights fp32 -> bf16, packed [Wq|Wk|Wv|Wo], each 512x512 row-major
// ---------------------------------------------------------------------------
__global__ __launch_bounds__(256) void k_cvt_w(const float* __restrict__ Wq,
                                               const float* __restrict__ Wk,
                                               const float* __restrict__ Wv,
                                               const float* __restrict__ Wo,
                                               bf16* __restrict__ Wb) {
    int tid = blockIdx.x * 256 + threadIdx.x;
    int idx = tid * 8;
    int mat = idx >> 18;
    int off = idx & 262143;
    const float* s = (mat == 0) ? Wq : (mat == 1) ? Wk : (mat == 2) ? Wv : Wo;
    const float4* s4 = (const float4*)(s + off);
    float4 u = s4[0], v = s4[1];
    bf16x8 o;
    o[0] = (bf16)u.x; o[1] = (bf16)u.y; o[2] = (bf16)u.z; o[3] = (bf16)u.w;
    o[4] = (bf16)v.x; o[5] = (bf16)v.y; o[6] = (bf16)v.z; o[7] = (bf16)v.w;
    *(bf16x8*)(Wb + idx) = o;
}

// ---------------------------------------------------------------------------
// K1: fused QKV GEMM + phi + per-(sub,head) partial KV / ksum.
//     512 threads = 8 waves; wave group (w>>2) handles even/odd head of each
//     round -> 2 waves/SIMD TLP, no duplicate weight loads. KV partials are
//     lane-packed (2 coalesced bf16x8 stores); k_red un-permutes.
// ---------------------------------------------------------------------------
__global__ __launch_bounds__(512, 1) void k_qkv(const bf16* __restrict__ xbT,
                                                const bf16* __restrict__ Wb,
                                                bf16* __restrict__ phiQ,
                                                bf16* __restrict__ kvP,
                                                float* __restrict__ ksP) {
    int bid = blockIdx.x;            // b*8 + st8
    int st8 = bid & 7, b = bid >> 3;
    int t = threadIdx.x, lane = t & 63, w = t >> 6;   // w in 0..7
    int l15 = lane & 15, g = lane >> 4;
    int wq  = w & 3;                 // d-quad within the head
    int grp = w >> 2;                // 0: even head, 1: odd head

    __shared__ bf16 xT[64][520];     // 66.5 KB  [s][c] full-k tile
    __shared__ bf16 pq[64][264];     // 33.8 KB  phiQ cols for 4 heads at a time
    __shared__ bf16 pk[2][64][72];   // 18.4 KB  phi(K) [d][s] per group
    __shared__ bf16 vv[2][64][72];   // 18.4 KB  V      [e][s] per group
    __shared__ float ksl[512];       //  2.0 KB  ksum accumulator [h*64+d]

    ksl[t] = 0.f;

#pragma unroll 1
    for (int sub = 0; sub < 2; ++sub) {
        int srow0 = st8 * 128 + sub * 64;
        // stage x^T tile [64 s][512 c]
        {
            int sr = t >> 3;
            const bf16* src = xbT + ((size_t)b * Sn + srow0 + sr) * Cn;
#pragma unroll
            for (int it = 0; it < 8; ++it) {
                int c0 = (t & 7) * 8 + it * 64;
                *(bf16x8*)&xT[sr][c0] = *(const bf16x8*)(src + c0);
            }
        }
        __syncthreads();             // A: xT ready (also fences ksl init / pq flush)

#pragma unroll 1
        for (int j = 0; j < 4; ++j) {
            int hh = j * 2 + grp;    // this wave-group's head
            int arow = hh * 64 + wq * 16 + l15;
            f32x4 accQ[4], accK[4], accV[4];
#pragma unroll
            for (int n = 0; n < 4; ++n) {
                accQ[n] = (f32x4){0.f,0.f,0.f,0.f};
                accK[n] = (f32x4){0.f,0.f,0.f,0.f};
                accV[n] = (f32x4){0.f,0.f,0.f,0.f};
            }
            // k-loop: 4 chunks of 4 k-steps; unroll 2 bounds frag liveness
#pragma unroll 2
            for (int kc = 0; kc < 4; ++kc) {
                bf16x8 aq[4], ak[4], av[4];
                const bf16* w0 = Wb + (size_t)arow * 512 + kc * 128 + g * 8;
#pragma unroll
                for (int jj = 0; jj < 4; ++jj) {
                    aq[jj] = *(const bf16x8*)(w0 + jj * 32);
                    ak[jj] = *(const bf16x8*)(w0 + 262144 + jj * 32);
                    av[jj] = *(const bf16x8*)(w0 + 524288 + jj * 32);
                }
#pragma unroll
                for (int k = 0; k < 4; ++k) {
#pragma unroll
                    for (int n = 0; n < 4; ++n) {
                        bf16x8 bfrag = *(const bf16x8*)&xT[n * 16 + l15][(kc * 4 + k) * 32 + g * 8];
                        accQ[n] = MFMA16(aq[k], bfrag, accQ[n]);
                        accK[n] = MFMA16(ak[k], bfrag, accK[n]);
                        accV[n] = MFMA16(av[k], bfrag, accV[n]);
                    }
                }
            }
            __syncthreads();         // B: prev round's pk/vv reads done
            // phi + writes (C-layout: row d = wq*16+g*4+r, col s = n*16+l15)
            float kspart[4] = {0.f, 0.f, 0.f, 0.f};
#pragma unroll
            for (int n = 0; n < 4; ++n) {
                bf16x4 qv;
#pragma unroll
                for (int r = 0; r < 4; ++r) {
                    float kv_ = accK[n][r];
                    kv_ = kv_ > 0.f ? kv_ + 1.f : __expf(kv_);
                    bf16 kb = (bf16)kv_;
                    kspart[r] += (float)kb;
                    pk[grp][wq * 16 + g * 4 + r][n * 16 + l15] = kb;
                    vv[grp][wq * 16 + g * 4 + r][n * 16 + l15] = (bf16)accV[n][r];
                    float q = accQ[n][r];
                    q = q > 0.f ? q + 1.f : __expf(q);
                    qv[r] = (bf16)q;
                }
                *(bf16x4*)&pq[n * 16 + l15][(hh & 3) * 64 + wq * 16 + g * 4] = qv;
            }
            // ksum: reduce over the 16-lane group, owner lane accumulates in LDS
#pragma unroll
            for (int r = 0; r < 4; ++r) {
                float v = kspart[r];
                v += __shfl_xor(v, 1);
                v += __shfl_xor(v, 2);
                v += __shfl_xor(v, 4);
                v += __shfl_xor(v, 8);
                if (l15 == 0) ksl[hh * 64 + wq * 16 + g * 4 + r] += v;
            }
            __syncthreads();         // C: pk/vv (and pq for flush) ready
            // KV partial: m=d, n=e, k=s (64 s -> 2 k-steps)
            f32x4 kvacc[4];
#pragma unroll
            for (int n = 0; n < 4; ++n) kvacc[n] = (f32x4){0.f,0.f,0.f,0.f};
#pragma unroll
            for (int k2 = 0; k2 < 2; ++k2) {
                bf16x8 afrag = *(const bf16x8*)&pk[grp][wq * 16 + l15][k2 * 32 + g * 8];
#pragma unroll
                for (int n = 0; n < 4; ++n) {
                    bf16x8 bfrag = *(const bf16x8*)&vv[grp][n * 16 + l15][k2 * 32 + g * 8];
                    kvacc[n] = MFMA16(afrag, bfrag, kvacc[n]);
                }
            }
            // lane-packed coalesced store of the KV partial (k_red un-permutes):
            // value (n,r) of lane (wq*64+lane) is KV[d=wq*16+g*4+r][e=n*16+l15]
            {
                bf16x8 p0, p1;
#pragma unroll
                for (int r = 0; r < 4; ++r) {
                    p0[r]     = (bf16)kvacc[0][r];
                    p0[4 + r] = (bf16)kvacc[1][r];
                    p1[r]     = (bf16)kvacc[2][r];
                    p1[4 + r] = (bf16)kvacc[3][r];
                }
                size_t base = ((size_t)((b * 8 + hh) * 16 + st8 * 2 + sub)) * 4096;
                bf16* dst = kvP + base + (size_t)(wq * 64 + lane) * 16;
                *(bf16x8*)(dst)     = p0;
                *(bf16x8*)(dst + 8) = p1;
            }
            // pq flush: rounds 0-1 fill heads 0-3 (cols 0-255), 2-3 fill 4-7
            if (j == 1 || j == 3) {
                int cbase = (j == 1) ? 0 : 256;
                int sr = t >> 3;
                bf16* dst = phiQ + ((size_t)b * Sn + srow0 + sr) * Cn + cbase + (t & 7) * 32;
#pragma unroll
                for (int jj = 0; jj < 4; ++jj)
                    *(bf16x8*)(dst + jj * 8) = *(const bf16x8*)&pq[sr][(t & 7) * 32 + jj * 8];
            }
        }
    }
    // epilogue: partial ksum -> ksP
    __syncthreads();
    {
        int h = t >> 6, d = t & 63;
        ksP[((b * 8 + h) * 8 + st8) * 64 + d] = ksl[t];
    }
}

// ---------------------------------------------------------------------------
// K2: reduce lane-packed partials -> KVT[bh][e][d] bf16, ksum[bh][d] fp32.
//     slot = wq*64 + lane; value idx = n*4+r -> (d = wq*16+g*4+r, e = n*16+l15)
// ---------------------------------------------------------------------------
__global__ __launch_bounds__(256) void k_red(const bf16* __restrict__ kvP,
                                             const float* __restrict__ ksP,
                                             bf16* __restrict__ KVT,
                                             float* __restrict__ ksum) {
    int bh = blockIdx.x;
    int t = threadIdx.x;             // slot
    int wq = t >> 6, lane = t & 63, g = lane >> 4, l15 = lane & 15;
    float acc[16];
#pragma unroll
    for (int i = 0; i < 16; ++i) acc[i] = 0.f;
#pragma unroll
    for (int p = 0; p < 16; ++p) {
        const bf16* src = kvP + ((size_t)bh * 16 + p) * 4096 + (size_t)t * 16;
        bf16x8 v0 = *(const bf16x8*)(src);
        bf16x8 v1 = *(const bf16x8*)(src + 8);
#pragma unroll
        for (int i = 0; i < 8; ++i) { acc[i] += (float)v0[i]; acc[8 + i] += (float)v1[i]; }
    }
#pragma unroll
    for (int n = 0; n < 4; ++n) {
        bf16x4 o;
#pragma unroll
        for (int r = 0; r < 4; ++r) o[r] = (bf16)acc[n * 4 + r];
        *(bf16x4*)(KVT + (size_t)bh * 4096 + (n * 16 + l15) * 64 + wq * 16 + g * 4) = o;
    }
    if (t < 64) {
        float s = 0.f;
#pragma unroll
        for (int p = 0; p < 8; ++p) s += ksP[((size_t)bh * 8 + p) * 64 + t];
        ksum[bh * 64 + t] = s;
    }
}

// ---------------------------------------------------------------------------
// K3: apply + output GEMM, per (b, s-tile of 64):
//     denom (all heads, one parallel phase), numerator MFMA per head writing
//     O in-place into the phiQ LDS buffer (disjoint columns), then
//     out = Wo @ O^T + bo  (fp32 coalesced stores).
// ---------------------------------------------------------------------------
__global__ __launch_bounds__(256, 1) void k_apply(const bf16* __restrict__ phiQ,
                                                  const bf16* __restrict__ Wb,
                                                  const bf16* __restrict__ KVT,
                                                  const float* __restrict__ ksum,
                                                  const float* __restrict__ bo,
                                                  float* __restrict__ out) {
    int bid = blockIdx.x;            // b*16 + st
    int st = bid & 15, b = bid >> 4;
    int t = threadIdx.x, lane = t & 63, w = t >> 6, l15 = lane & 15, g = lane >> 4;

    __shared__ bf16 pq[64][520];     // phiQ tile, later reused per-head as O
    __shared__ float ksl[512];
    __shared__ float rden[64][8];
    __shared__ float bol[512];

    {
        int sr = t >> 2;
        const bf16* src = phiQ + ((size_t)b * Sn + st * 64 + sr) * Cn;
#pragma unroll
        for (int it = 0; it < 16; ++it) {
            int c0 = (t & 3) * 8 + it * 32;
            *(bf16x8*)&pq[sr][c0] = *(const bf16x8*)(src + c0);
        }
        ksl[t] = ksum[b * 512 + t];
        ksl[t + 256] = ksum[b * 512 + t + 256];
        bol[t] = bo[t];
        bol[t + 256] = bo[t + 256];
    }
    __syncthreads();
    // denominators: 512 jobs (s,h), 2 per thread
#pragma unroll
    for (int rep = 0; rep < 2; ++rep) {
        int j = rep * 256 + t;
        int s = j & 63, h = j >> 6;
        float acc = 0.f;
#pragma unroll
        for (int dt = 0; dt < 8; ++dt) {
            bf16x8 v = *(const bf16x8*)&pq[s][h * 64 + dt * 8];
#pragma unroll
            for (int i = 0; i < 8; ++i) acc += ksl[h * 64 + dt * 8 + i] * (float)v[i];
        }
        rden[s][h] = 1.f / (acc + 1e-6f);
    }
    __syncthreads();
    // numerator per head; O overwrites pq columns of that head
    for (int h = 0; h < 8; ++h) {
        const bf16* kvb = KVT + ((size_t)(b * 8 + h)) * 4096 + (w * 16 + l15) * 64;
        f32x4 accN[4];
#pragma unroll
        for (int n = 0; n < 4; ++n) accN[n] = (f32x4){0.f,0.f,0.f,0.f};
#pragma unroll
        for (int k2 = 0; k2 < 2; ++k2) {
            bf16x8 afrag = *(const bf16x8*)(kvb + k2 * 32 + g * 8);
#pragma unroll
            for (int n = 0; n < 4; ++n) {
                bf16x8 bfrag = *(const bf16x8*)&pq[n * 16 + l15][h * 64 + k2 * 32 + g * 8];
                accN[n] = MFMA16(afrag, bfrag, accN[n]);
            }
        }
        __syncthreads();             // all reads of pq cols h done before overwrite
#pragma unroll
        for (int n = 0; n < 4; ++n) {
            float rd = rden[n * 16 + l15][h];
            bf16x4 ov;
#pragma unroll
            for (int r = 0; r < 4; ++r) ov[r] = (bf16)(accN[n][r] * rd);
            *(bf16x4*)&pq[n * 16 + l15][h * 64 + w * 16 + g * 4] = ov;
        }
    }
    __syncthreads();
    // out = Wo @ O^T + bo
    const bf16* Wob = Wb + 786432;
    for (int mt = 0; mt < 8; ++mt) {
        int m0 = w * 128 + mt * 16;
        const bf16* wrow = Wob + (size_t)(m0 + l15) * 512;
        f32x4 acc[4];
#pragma unroll
        for (int n = 0; n < 4; ++n) acc[n] = (f32x4){0.f,0.f,0.f,0.f};
#pragma unroll
        for (int k = 0; k < 16; ++k) {
            bf16x8 afrag = *(const bf16x8*)(wrow + k * 32 + g * 8);
#pragma unroll
            for (int n = 0; n < 4; ++n) {
                bf16x8 bfrag = *(const bf16x8*)&pq[n * 16 + l15][k * 32 + g * 8];
                acc[n] = MFMA16(afrag, bfrag, acc[n]);
            }
        }
#pragma unroll
        for (int r = 0; r < 4; ++r) {
            int co = m0 + g * 4 + r;
            float bb = bol[co];
#pragma unroll
            for (int n = 0; n < 4; ++n)
                out[((size_t)b * Cn + co) * Sn + st * 64 + n * 16 + l15] = acc[n][r] + bb;
        }
    }
}

// ---------------------------------------------------------------------------
extern "C" void kernel_launch(void* const* d_in, const int* in_sizes, int n_in,
                              void* d_out, int out_size, void* d_ws, size_t ws_size,
                              hipStream_t stream) {
    const float* x  = (const float*)d_in[0];
    const float* Wq = (const float*)d_in[1];
    const float* Wk = (const float*)d_in[2];
    const float* Wv = (const float*)d_in[3];
    const float* Wo = (const float*)d_in[4];
    const float* bo = (const float*)d_in[5];
    float* out = (float*)d_out;

    char* ws = (char*)d_ws;
    bf16*  xbT  = (bf16*)ws;                       // 33,554,432 B — aliased as phiQ
    bf16*  Wb   = (bf16*)(ws + 33554432);          //  2,097,152 B
    float* ksP  = (float*)(ws + 35651584);         //    524,288 B
    bf16*  KVT  = (bf16*)(ws + 36175872);          //  2,097,152 B
    float* ks   = (float*)(ws + 38273024);         //     65,536 B   (total 38.3 MB)

    // KV partials (32 MB) alias d_out: fully written by k_qkv, consumed by
    // k_red, then k_apply overwrites the whole output buffer.
    bf16*  kvP  = (bf16*)d_out;

    k_transpose<<<4096, 256, 0, stream>>>(x, xbT);
    k_cvt_w   <<< 512, 256, 0, stream>>>(Wq, Wk, Wv, Wo, Wb);
    k_qkv     <<< 256, 512, 0, stream>>>(xbT, Wb, xbT /*phiQ alias*/, kvP, ksP);
    k_red     <<< 256, 256, 0, stream>>>(kvP, ksP, KVT, ks);
    k_apply   <<< 512, 256, 0, stream>>>(xbT /*phiQ*/, Wb, KVT, ks, bo, out);
}

// Round 6
// 217.895 us; speedup vs baseline: 2.5622x; 1.0652x over previous
//
#include <hip/hip_runtime.h>
#include <hip/hip_bf16.h>

typedef __bf16 bf16;
typedef __bf16 bf16x2 __attribute__((ext_vector_type(2)));
typedef __bf16 bf16x4 __attribute__((ext_vector_type(4)));
typedef __bf16 bf16x8 __attribute__((ext_vector_type(8)));
typedef float  f32x4  __attribute__((ext_vector_type(4)));

#define MFMA16(a,b,c) __builtin_amdgcn_mfma_f32_16x16x32_bf16((a),(b),(c),0,0,0)

// Problem constants: B=32, C=E=512, H=W=32 -> S=1024, 8 heads x 64
constexpr int Cn = 512;
constexpr int Sn = 1024;

// ---------------------------------------------------------------------------
// K0: weights fp32 -> bf16, packed [Wq|Wk|Wv|Wo], each 512x512 row-major
// ---------------------------------------------------------------------------
__global__ __launch_bounds__(256) void k_cvt_w(const float* __restrict__ Wq,
                                               const float* __restrict__ Wk,
                                               const float* __restrict__ Wv,
                                               const float* __restrict__ Wo,
                                               bf16* __restrict__ Wb) {
    int tid = blockIdx.x * 256 + threadIdx.x;
    int idx = tid * 8;
    int mat = idx >> 18;
    int off = idx & 262143;
    const float* s = (mat == 0) ? Wq : (mat == 1) ? Wk : (mat == 2) ? Wv : Wo;
    const float4* s4 = (const float4*)(s + off);
    float4 u = s4[0], v = s4[1];
    bf16x8 o;
    o[0] = (bf16)u.x; o[1] = (bf16)u.y; o[2] = (bf16)u.z; o[3] = (bf16)u.w;
    o[4] = (bf16)v.x; o[5] = (bf16)v.y; o[6] = (bf16)v.z; o[7] = (bf16)v.w;
    *(bf16x8*)(Wb + idx) = o;
}

// ---------------------------------------------------------------------------
// K1: fused transpose + QKV GEMM + phi + per-(sub,head) partial KV / ksum.
//     grid = (b, st8): 256 blocks x 1024 threads (16 waves, 4/SIMD).
//     Per sub (64 s-rows): stage x fp32 -> xT bf16 (in-LDS transpose), then
//     2 rounds of 4 heads: wave = (head, d-quad): M=16, acc 48 VGPR (fits the
//     128-VGPR/16-wave budget). phiQ stored direct-to-global; KV partial MFMA
//     by all 16 waves; kvP lane-packed (aliases d_out). 5 barriers/sub.
// ---------------------------------------------------------------------------
__global__ __launch_bounds__(1024, 4) void k_qkv(const float* __restrict__ x,
                                                 const bf16* __restrict__ Wb,
                                                 bf16* __restrict__ phiQ,
                                                 bf16* __restrict__ kvP,
                                                 float* __restrict__ ksP) {
    int bid = blockIdx.x;            // b*8 + st8
    int st8 = bid & 7, b = bid >> 3;
    int t = threadIdx.x, lane = t & 63, w = t >> 6;   // w in 0..15
    int l15 = lane & 15, g = lane >> 4;
    int hq   = w >> 2;               // head-within-round (0..3)
    int quad = w & 3;                // d-quad within head

    __shared__ bf16 xT[64][520];     // 66.5 KB [s][c] full-k tile
    __shared__ bf16 pk[4][64][72];   // 36.9 KB phi(K) [d][s], 4 heads/round
    __shared__ bf16 vv[4][64][72];   // 36.9 KB V      [e][s]
    __shared__ float ksl[512];       //  2.0 KB ksum accumulator [h*64+d]

    if (t < 512) ksl[t] = 0.f;

    int cpair = t & 255;             // c rows 2*cpair, 2*cpair+1
    int sq    = t >> 8;              // s-quarter (16 s each)

#pragma unroll 1
    for (int sub = 0; sub < 2; ++sub) {
        int srow0 = st8 * 128 + sub * 64;
        // ---- stage: x fp32 [c][s] -> xT bf16 [s][c] (transpose in LDS) ----
        {
            const float* xr = x + ((size_t)b * Cn + 2 * cpair) * Sn + srow0 + sq * 16;
            float4 f0[4], f1[4];
#pragma unroll
            for (int j = 0; j < 4; ++j) {
                f0[j] = ((const float4*)xr)[j];
                f1[j] = ((const float4*)(xr + Sn))[j];
            }
#pragma unroll
            for (int j = 0; j < 4; ++j) {
                const float* e0 = (const float*)&f0[j];
                const float* e1 = (const float*)&f1[j];
#pragma unroll
                for (int e = 0; e < 4; ++e) {
                    int s = sq * 16 + j * 4 + e;
                    bf16x2 pr;
                    pr[0] = (bf16)e0[e];
                    pr[1] = (bf16)e1[e];
                    *(bf16x2*)&xT[s][2 * cpair] = pr;   // b32 write, ~2-way
                }
            }
        }
        __syncthreads();             // BAR1: xT ready; prev KV reads done

#pragma unroll 1
        for (int rnd = 0; rnd < 2; ++rnd) {
            int h = rnd * 4 + hq;
            // ---- QKV compute: M=16 rows (h,quad), N=64, full k=512 ----
            f32x4 aQ[4], aK[4], aV[4];
#pragma unroll
            for (int n = 0; n < 4; ++n) {
                aQ[n] = (f32x4){0.f,0.f,0.f,0.f};
                aK[n] = (f32x4){0.f,0.f,0.f,0.f};
                aV[n] = (f32x4){0.f,0.f,0.f,0.f};
            }
            const bf16* wr = Wb + (size_t)(h * 64 + quad * 16 + l15) * 512 + g * 8;
#pragma unroll 1
            for (int kc = 0; kc < 8; ++kc) {
                bf16x8 fq[2], fk[2], fv[2];
#pragma unroll
                for (int kk = 0; kk < 2; ++kk) {
                    const bf16* p = wr + (kc * 2 + kk) * 32;
                    fq[kk] = *(const bf16x8*)(p);
                    fk[kk] = *(const bf16x8*)(p + 262144);
                    fv[kk] = *(const bf16x8*)(p + 524288);
                }
#pragma unroll
                for (int kk = 0; kk < 2; ++kk) {
#pragma unroll
                    for (int n = 0; n < 4; ++n) {
                        bf16x8 bf_ = *(const bf16x8*)&xT[n * 16 + l15][(kc * 2 + kk) * 32 + g * 8];
                        aQ[n] = MFMA16(fq[kk], bf_, aQ[n]);
                        aK[n] = MFMA16(fk[kk], bf_, aK[n]);
                        aV[n] = MFMA16(fv[kk], bf_, aV[n]);
                    }
                }
            }
            // ---- phi; pk/vv LDS writes; phiQ direct global; ksum ----
            float kspart[4] = {0.f, 0.f, 0.f, 0.f};
#pragma unroll
            for (int n = 0; n < 4; ++n) {
                bf16x4 qv;
#pragma unroll
                for (int r = 0; r < 4; ++r) {
                    float kv_ = aK[n][r];
                    kv_ = kv_ > 0.f ? kv_ + 1.f : __expf(kv_);
                    bf16 kb = (bf16)kv_;
                    kspart[r] += (float)kb;
                    pk[hq][quad * 16 + g * 4 + r][n * 16 + l15] = kb;
                    vv[hq][quad * 16 + g * 4 + r][n * 16 + l15] = (bf16)aV[n][r];
                    float q = aQ[n][r];
                    q = q > 0.f ? q + 1.f : __expf(q);
                    qv[r] = (bf16)q;
                }
                *(bf16x4*)(phiQ + ((size_t)b * Sn + srow0 + n * 16 + l15) * Cn
                           + h * 64 + quad * 16 + g * 4) = qv;
            }
#pragma unroll
            for (int r = 0; r < 4; ++r) {
                float v = kspart[r];
                v += __shfl_xor(v, 1);
                v += __shfl_xor(v, 2);
                v += __shfl_xor(v, 4);
                v += __shfl_xor(v, 8);
                if (l15 == 0) ksl[h * 64 + quad * 16 + g * 4 + r] += v;
            }
            __syncthreads();         // BAR2: pk/vv of this round ready
            // ---- KV partial MFMA: all 16 waves, m = quad of head h ----
            f32x4 kvacc[4];
#pragma unroll
            for (int n = 0; n < 4; ++n) kvacc[n] = (f32x4){0.f,0.f,0.f,0.f};
#pragma unroll
            for (int k2 = 0; k2 < 2; ++k2) {
                bf16x8 af = *(const bf16x8*)&pk[hq][quad * 16 + l15][k2 * 32 + g * 8];
#pragma unroll
                for (int n = 0; n < 4; ++n) {
                    bf16x8 bf_ = *(const bf16x8*)&vv[hq][n * 16 + l15][k2 * 32 + g * 8];
                    kvacc[n] = MFMA16(af, bf_, kvacc[n]);
                }
            }
            // lane-packed coalesced store (k_red un-permutes):
            // value (n,r) of slot (quad*64+lane) = KV[d=quad*16+g*4+r][e=n*16+l15]
            {
                bf16x8 p0, p1;
#pragma unroll
                for (int r = 0; r < 4; ++r) {
                    p0[r]     = (bf16)kvacc[0][r];
                    p0[4 + r] = (bf16)kvacc[1][r];
                    p1[r]     = (bf16)kvacc[2][r];
                    p1[4 + r] = (bf16)kvacc[3][r];
                }
                size_t base = ((size_t)((b * 8 + h) * 16 + st8 * 2 + sub)) * 4096;
                bf16* dst = kvP + base + (size_t)(quad * 64 + lane) * 16;
                *(bf16x8*)(dst)     = p0;
                *(bf16x8*)(dst + 8) = p1;
            }
            __syncthreads();         // BAR3: KV reads done before next round's writes
        }
    }
    // epilogue: partial ksum -> ksP
    if (t < 512) {
        int h = t >> 6, d = t & 63;
        ksP[((b * 8 + h) * 8 + st8) * 64 + d] = ksl[t];
    }
}

// ---------------------------------------------------------------------------
// K2: reduce lane-packed partials -> KVT[bh][e][d] bf16, ksum[bh][d] fp32.
//     slot = wq*64 + lane; value idx = n*4+r -> (d = wq*16+g*4+r, e = n*16+l15)
// ---------------------------------------------------------------------------
__global__ __launch_bounds__(256) void k_red(const bf16* __restrict__ kvP,
                                             const float* __restrict__ ksP,
                                             bf16* __restrict__ KVT,
                                             float* __restrict__ ksum) {
    int bh = blockIdx.x;
    int t = threadIdx.x;             // slot
    int wq = t >> 6, lane = t & 63, g = lane >> 4, l15 = lane & 15;
    float acc[16];
#pragma unroll
    for (int i = 0; i < 16; ++i) acc[i] = 0.f;
#pragma unroll
    for (int p = 0; p < 16; ++p) {
        const bf16* src = kvP + ((size_t)bh * 16 + p) * 4096 + (size_t)t * 16;
        bf16x8 v0 = *(const bf16x8*)(src);
        bf16x8 v1 = *(const bf16x8*)(src + 8);
#pragma unroll
        for (int i = 0; i < 8; ++i) { acc[i] += (float)v0[i]; acc[8 + i] += (float)v1[i]; }
    }
#pragma unroll
    for (int n = 0; n < 4; ++n) {
        bf16x4 o;
#pragma unroll
        for (int r = 0; r < 4; ++r) o[r] = (bf16)acc[n * 4 + r];
        *(bf16x4*)(KVT + (size_t)bh * 4096 + (n * 16 + l15) * 64 + wq * 16 + g * 4) = o;
    }
    if (t < 64) {
        float s = 0.f;
#pragma unroll
        for (int p = 0; p < 8; ++p) s += ksP[((size_t)bh * 8 + p) * 64 + t];
        ksum[bh * 64 + t] = s;
    }
}

// ---------------------------------------------------------------------------
// K3: apply + output GEMM, per (b, s-tile of 64):
//     denom (all heads, one parallel phase), numerator MFMA per head writing
//     O in-place into the phiQ LDS buffer (disjoint columns), then
//     out = Wo @ O^T + bo  (fp32 coalesced stores).
// ---------------------------------------------------------------------------
__global__ __launch_bounds__(256, 1) void k_apply(const bf16* __restrict__ phiQ,
                                                  const bf16* __restrict__ Wb,
                                                  const bf16* __restrict__ KVT,
                                                  const float* __restrict__ ksum,
                                                  const float* __restrict__ bo,
                                                  float* __restrict__ out) {
    int bid = blockIdx.x;            // b*16 + st
    int st = bid & 15, b = bid >> 4;
    int t = threadIdx.x, lane = t & 63, w = t >> 6, l15 = lane & 15, g = lane >> 4;

    __shared__ bf16 pq[64][520];     // phiQ tile, later reused per-head as O
    __shared__ float ksl[512];
    __shared__ float rden[64][8];
    __shared__ float bol[512];

    {
        int sr = t >> 2;
        const bf16* src = phiQ + ((size_t)b * Sn + st * 64 + sr) * Cn;
#pragma unroll
        for (int it = 0; it < 16; ++it) {
            int c0 = (t & 3) * 8 + it * 32;
            *(bf16x8*)&pq[sr][c0] = *(const bf16x8*)(src + c0);
        }
        ksl[t] = ksum[b * 512 + t];
        ksl[t + 256] = ksum[b * 512 + t + 256];
        bol[t] = bo[t];
        bol[t + 256] = bo[t + 256];
    }
    __syncthreads();
    // denominators: 512 jobs (s,h), 2 per thread
#pragma unroll
    for (int rep = 0; rep < 2; ++rep) {
        int j = rep * 256 + t;
        int s = j & 63, h = j >> 6;
        float acc = 0.f;
#pragma unroll
        for (int dt = 0; dt < 8; ++dt) {
            bf16x8 v = *(const bf16x8*)&pq[s][h * 64 + dt * 8];
#pragma unroll
            for (int i = 0; i < 8; ++i) acc += ksl[h * 64 + dt * 8 + i] * (float)v[i];
        }
        rden[s][h] = 1.f / (acc + 1e-6f);
    }
    __syncthreads();
    // numerator per head; O overwrites pq columns of that head
    for (int h = 0; h < 8; ++h) {
        const bf16* kvb = KVT + ((size_t)(b * 8 + h)) * 4096 + (w * 16 + l15) * 64;
        f32x4 accN[4];
#pragma unroll
        for (int n = 0; n < 4; ++n) accN[n] = (f32x4){0.f,0.f,0.f,0.f};
#pragma unroll
        for (int k2 = 0; k2 < 2; ++k2) {
            bf16x8 afrag = *(const bf16x8*)(kvb + k2 * 32 + g * 8);
#pragma unroll
            for (int n = 0; n < 4; ++n) {
                bf16x8 bfrag = *(const bf16x8*)&pq[n * 16 + l15][h * 64 + k2 * 32 + g * 8];
                accN[n] = MFMA16(afrag, bfrag, accN[n]);
            }
        }
        __syncthreads();             // all reads of pq cols h done before overwrite
#pragma unroll
        for (int n = 0; n < 4; ++n) {
            float rd = rden[n * 16 + l15][h];
            bf16x4 ov;
#pragma unroll
            for (int r = 0; r < 4; ++r) ov[r] = (bf16)(accN[n][r] * rd);
            *(bf16x4*)&pq[n * 16 + l15][h * 64 + w * 16 + g * 4] = ov;
        }
    }
    __syncthreads();
    // out = Wo @ O^T + bo
    const bf16* Wob = Wb + 786432;
    for (int mt = 0; mt < 8; ++mt) {
        int m0 = w * 128 + mt * 16;
        const bf16* wrow = Wob + (size_t)(m0 + l15) * 512;
        f32x4 acc[4];
#pragma unroll
        for (int n = 0; n < 4; ++n) acc[n] = (f32x4){0.f,0.f,0.f,0.f};
#pragma unroll
        for (int k = 0; k < 16; ++k) {
            bf16x8 afrag = *(const bf16x8*)(wrow + k * 32 + g * 8);
#pragma unroll
            for (int n = 0; n < 4; ++n) {
                bf16x8 bfrag = *(const bf16x8*)&pq[n * 16 + l15][k * 32 + g * 8];
                acc[n] = MFMA16(afrag, bfrag, acc[n]);
            }
        }
#pragma unroll
        for (int r = 0; r < 4; ++r) {
            int co = m0 + g * 4 + r;
            float bb = bol[co];
#pragma unroll
            for (int n = 0; n < 4; ++n)
                out[((size_t)b * Cn + co) * Sn + st * 64 + n * 16 + l15] = acc[n][r] + bb;
        }
    }
}

// ---------------------------------------------------------------------------
extern "C" void kernel_launch(void* const* d_in, const int* in_sizes, int n_in,
                              void* d_out, int out_size, void* d_ws, size_t ws_size,
                              hipStream_t stream) {
    const float* x  = (const float*)d_in[0];
    const float* Wq = (const float*)d_in[1];
    const float* Wk = (const float*)d_in[2];
    const float* Wv = (const float*)d_in[3];
    const float* Wo = (const float*)d_in[4];
    const float* bo = (const float*)d_in[5];
    float* out = (float*)d_out;

    char* ws = (char*)d_ws;
    bf16*  phiQ = (bf16*)ws;                       // 33,554,432 B
    bf16*  Wb   = (bf16*)(ws + 33554432);          //  2,097,152 B
    float* ksP  = (float*)(ws + 35651584);         //    524,288 B
    bf16*  KVT  = (bf16*)(ws + 36175872);          //  2,097,152 B
    float* ks   = (float*)(ws + 38273024);         //     65,536 B   (total 38.3 MB)

    // KV partials (32 MB) alias d_out: fully written by k_qkv, consumed by
    // k_red, then k_apply overwrites the whole output buffer.
    bf16*  kvP  = (bf16*)d_out;

    k_cvt_w <<< 512,  256, 0, stream>>>(Wq, Wk, Wv, Wo, Wb);
    k_qkv   <<< 256, 1024, 0, stream>>>(x, Wb, phiQ, kvP, ksP);
    k_red   <<< 256,  256, 0, stream>>>(kvP, ksP, KVT, ks);
    k_apply <<< 512,  256, 0, stream>>>(phiQ, Wb, KVT, ks, bo, out);
}

// Round 7
// 167.851 us; speedup vs baseline: 3.3261x; 1.2981x over previous
//
#include <hip/hip_runtime.h>
#include <hip/hip_bf16.h>

typedef __bf16 bf16;
typedef __bf16 bf16x2 __attribute__((ext_vector_type(2)));
typedef __bf16 bf16x4 __attribute__((ext_vector_type(4)));
typedef __bf16 bf16x8 __attribute__((ext_vector_type(8)));
typedef float  f32x4  __attribute__((ext_vector_type(4)));

#define MFMA16(a,b,c) __builtin_amdgcn_mfma_f32_16x16x32_bf16((a),(b),(c),0,0,0)

// Problem constants: B=32, C=E=512, H=W=32 -> S=1024, 8 heads x 64
constexpr int Cn = 512;
constexpr int Sn = 1024;

// ---------------------------------------------------------------------------
// K0: weights fp32 -> bf16. Wq/Wk/Wv are emitted in MFMA-A-fragment order:
//     WF[((m*32+gr)*16 + kc)*512 + lane*8 + i] = W[m][gr*16+(lane&15)][kc*32+(lane>>4)*8+i]
//     (gr = 16-row group, kc = 32-wide k-chunk). A wave's A-frag load for one
//     (matrix, k-chunk) is then a single contiguous 1KB block.
//     Wo stays row-major at offset 786432 (consumed by k_apply).
// ---------------------------------------------------------------------------
__global__ __launch_bounds__(256) void k_cvt_w(const float* __restrict__ Wq,
                                               const float* __restrict__ Wk,
                                               const float* __restrict__ Wv,
                                               const float* __restrict__ Wo,
                                               bf16* __restrict__ Wb) {
    int tid = blockIdx.x * 256 + threadIdx.x;   // 512 blocks x 256
    if (tid < 98304) {                          // fragged Wq|Wk|Wv
        int oidx = tid * 8;
        int m  = oidx >> 18;
        int r  = oidx & 262143;
        int gr = r >> 13;
        int kc = (r >> 9) & 15;
        int l  = (r >> 3) & 63;
        const float* s = (m == 0) ? Wq : (m == 1) ? Wk : Wv;
        const float* src = s + (gr * 16 + (l & 15)) * 512 + kc * 32 + (l >> 4) * 8;
        float4 u = ((const float4*)src)[0], v = ((const float4*)src)[1];
        bf16x8 o;
        o[0] = (bf16)u.x; o[1] = (bf16)u.y; o[2] = (bf16)u.z; o[3] = (bf16)u.w;
        o[4] = (bf16)v.x; o[5] = (bf16)v.y; o[6] = (bf16)v.z; o[7] = (bf16)v.w;
        *(bf16x8*)(Wb + oidx) = o;
    } else {                                    // Wo row-major
        int off = (tid - 98304) * 8;
        const float4* s4 = (const float4*)(Wo + off);
        float4 u = s4[0], v = s4[1];
        bf16x8 o;
        o[0] = (bf16)u.x; o[1] = (bf16)u.y; o[2] = (bf16)u.z; o[3] = (bf16)u.w;
        o[4] = (bf16)v.x; o[5] = (bf16)v.y; o[6] = (bf16)v.z; o[7] = (bf16)v.w;
        *(bf16x8*)(Wb + 786432 + off) = o;
    }
}

// ---------------------------------------------------------------------------
// K1: fused transpose + QKV GEMM + phi + per-(sub,head) partial KV / ksum.
//     grid = (b, st8): 256 blocks x 1024 threads (16 waves, 4/SIMD).
//     All global loads wave-contiguous: A-frags from fragged WF (1KB/load),
//     x staged with 4-lane 256B runs. kc loop unroll(2) for load batching.
// ---------------------------------------------------------------------------
__global__ __launch_bounds__(1024, 4) void k_qkv(const float* __restrict__ x,
                                                 const bf16* __restrict__ Wb,
                                                 bf16* __restrict__ phiQ,
                                                 bf16* __restrict__ kvP,
                                                 float* __restrict__ ksP) {
    int bid = blockIdx.x;            // b*8 + st8
    int st8 = bid & 7, b = bid >> 3;
    int t = threadIdx.x, lane = t & 63, w = t >> 6;   // w in 0..15
    int l15 = lane & 15, g = lane >> 4;
    int hq   = w >> 2;               // head-within-round (0..3)
    int quad = w & 3;                // d-quad within head

    __shared__ bf16 xT[64][520];     // 66.5 KB [s][c] full-k tile
    __shared__ bf16 pk[4][64][72];   // 36.9 KB phi(K) [d][s], 4 heads/round
    __shared__ bf16 vv[4][64][72];   // 36.9 KB V      [e][s]
    __shared__ float ksl[512];       //  2.0 KB ksum accumulator [h*64+d]

    if (t < 512) ksl[t] = 0.f;

    int rp = t >> 2;                 // row-pair: c rows 2rp, 2rp+1
    int sq = t & 3;                  // s-quarter (16 s each)

#pragma unroll 1
    for (int sub = 0; sub < 2; ++sub) {
        int srow0 = st8 * 128 + sub * 64;
        // ---- stage: x fp32 [c][s] -> xT bf16 [s][c]; 4 consecutive lanes
        //      read 256B runs of rows 2rp / 2rp+1 (coalesced) ----
        {
            const float* xr = x + ((size_t)b * Cn + 2 * rp) * Sn + srow0 + sq * 16;
            float4 f0[4], f1[4];
#pragma unroll
            for (int j = 0; j < 4; ++j) {
                f0[j] = ((const float4*)xr)[j];
                f1[j] = ((const float4*)(xr + Sn))[j];
            }
#pragma unroll
            for (int j = 0; j < 4; ++j) {
                const float* e0 = (const float*)&f0[j];
                const float* e1 = (const float*)&f1[j];
#pragma unroll
                for (int e = 0; e < 4; ++e) {
                    int s = sq * 16 + j * 4 + e;
                    bf16x2 pr;
                    pr[0] = (bf16)e0[e];
                    pr[1] = (bf16)e1[e];
                    *(bf16x2*)&xT[s][2 * rp] = pr;
                }
            }
        }
        __syncthreads();             // BAR1: xT ready; prev KV reads done

#pragma unroll 1
        for (int rnd = 0; rnd < 2; ++rnd) {
            int h = rnd * 4 + hq;
            int gr = h * 4 + quad;   // 16-row group index (0..31)
            // ---- QKV compute: M=16 rows (h,quad), N=64, full k=512 ----
            f32x4 aQ[4], aK[4], aV[4];
#pragma unroll
            for (int n = 0; n < 4; ++n) {
                aQ[n] = (f32x4){0.f,0.f,0.f,0.f};
                aK[n] = (f32x4){0.f,0.f,0.f,0.f};
                aV[n] = (f32x4){0.f,0.f,0.f,0.f};
            }
            const bf16* wfQ = Wb + ((size_t)(gr) * 16) * 512 + lane * 8;
            const bf16* wfK = wfQ + (size_t)32 * 16 * 512;
            const bf16* wfV = wfQ + (size_t)64 * 16 * 512;
#pragma unroll 2
            for (int kc = 0; kc < 16; ++kc) {
                bf16x8 fq = *(const bf16x8*)(wfQ + kc * 512);
                bf16x8 fk = *(const bf16x8*)(wfK + kc * 512);
                bf16x8 fv = *(const bf16x8*)(wfV + kc * 512);
#pragma unroll
                for (int n = 0; n < 4; ++n) {
                    bf16x8 bf_ = *(const bf16x8*)&xT[n * 16 + l15][kc * 32 + g * 8];
                    aQ[n] = MFMA16(fq, bf_, aQ[n]);
                    aK[n] = MFMA16(fk, bf_, aK[n]);
                    aV[n] = MFMA16(fv, bf_, aV[n]);
                }
            }
            // ---- phi; pk/vv LDS writes; phiQ direct global; ksum ----
            float kspart[4] = {0.f, 0.f, 0.f, 0.f};
#pragma unroll
            for (int n = 0; n < 4; ++n) {
                bf16x4 qv;
#pragma unroll
                for (int r = 0; r < 4; ++r) {
                    float kv_ = aK[n][r];
                    kv_ = kv_ > 0.f ? kv_ + 1.f : __expf(kv_);
                    bf16 kb = (bf16)kv_;
                    kspart[r] += (float)kb;
                    pk[hq][quad * 16 + g * 4 + r][n * 16 + l15] = kb;
                    vv[hq][quad * 16 + g * 4 + r][n * 16 + l15] = (bf16)aV[n][r];
                    float q = aQ[n][r];
                    q = q > 0.f ? q + 1.f : __expf(q);
                    qv[r] = (bf16)q;
                }
                *(bf16x4*)(phiQ + ((size_t)b * Sn + srow0 + n * 16 + l15) * Cn
                           + h * 64 + quad * 16 + g * 4) = qv;
            }
#pragma unroll
            for (int r = 0; r < 4; ++r) {
                float v = kspart[r];
                v += __shfl_xor(v, 1);
                v += __shfl_xor(v, 2);
                v += __shfl_xor(v, 4);
                v += __shfl_xor(v, 8);
                if (l15 == 0) ksl[h * 64 + quad * 16 + g * 4 + r] += v;
            }
            __syncthreads();         // BAR2: pk/vv of this round ready
            // ---- KV partial MFMA: all 16 waves, m = quad of head h ----
            f32x4 kvacc[4];
#pragma unroll
            for (int n = 0; n < 4; ++n) kvacc[n] = (f32x4){0.f,0.f,0.f,0.f};
#pragma unroll
            for (int k2 = 0; k2 < 2; ++k2) {
                bf16x8 af = *(const bf16x8*)&pk[hq][quad * 16 + l15][k2 * 32 + g * 8];
#pragma unroll
                for (int n = 0; n < 4; ++n) {
                    bf16x8 bf_ = *(const bf16x8*)&vv[hq][n * 16 + l15][k2 * 32 + g * 8];
                    kvacc[n] = MFMA16(af, bf_, kvacc[n]);
                }
            }
            // lane-packed coalesced store (k_red un-permutes):
            // value (n,r) of slot (quad*64+lane) = KV[d=quad*16+g*4+r][e=n*16+l15]
            {
                bf16x8 p0, p1;
#pragma unroll
                for (int r = 0; r < 4; ++r) {
                    p0[r]     = (bf16)kvacc[0][r];
                    p0[4 + r] = (bf16)kvacc[1][r];
                    p1[r]     = (bf16)kvacc[2][r];
                    p1[4 + r] = (bf16)kvacc[3][r];
                }
                size_t base = ((size_t)((b * 8 + h) * 16 + st8 * 2 + sub)) * 4096;
                bf16* dst = kvP + base + (size_t)(quad * 64 + lane) * 16;
                *(bf16x8*)(dst)     = p0;
                *(bf16x8*)(dst + 8) = p1;
            }
            __syncthreads();         // BAR3: KV reads done before next round's writes
        }
    }
    // epilogue: partial ksum -> ksP
    if (t < 512) {
        int h = t >> 6, d = t & 63;
        ksP[((b * 8 + h) * 8 + st8) * 64 + d] = ksl[t];
    }
}

// ---------------------------------------------------------------------------
// K2: reduce lane-packed partials -> KVT[bh][e][d] bf16, ksum[bh][d] fp32.
//     slot = wq*64 + lane; value idx = n*4+r -> (d = wq*16+g*4+r, e = n*16+l15)
// ---------------------------------------------------------------------------
__global__ __launch_bounds__(256) void k_red(const bf16* __restrict__ kvP,
                                             const float* __restrict__ ksP,
                                             bf16* __restrict__ KVT,
                                             float* __restrict__ ksum) {
    int bh = blockIdx.x;
    int t = threadIdx.x;             // slot
    int wq = t >> 6, lane = t & 63, g = lane >> 4, l15 = lane & 15;
    float acc[16];
#pragma unroll
    for (int i = 0; i < 16; ++i) acc[i] = 0.f;
#pragma unroll
    for (int p = 0; p < 16; ++p) {
        const bf16* src = kvP + ((size_t)bh * 16 + p) * 4096 + (size_t)t * 16;
        bf16x8 v0 = *(const bf16x8*)(src);
        bf16x8 v1 = *(const bf16x8*)(src + 8);
#pragma unroll
        for (int i = 0; i < 8; ++i) { acc[i] += (float)v0[i]; acc[8 + i] += (float)v1[i]; }
    }
#pragma unroll
    for (int n = 0; n < 4; ++n) {
        bf16x4 o;
#pragma unroll
        for (int r = 0; r < 4; ++r) o[r] = (bf16)acc[n * 4 + r];
        *(bf16x4*)(KVT + (size_t)bh * 4096 + (n * 16 + l15) * 64 + wq * 16 + g * 4) = o;
    }
    if (t < 64) {
        float s = 0.f;
#pragma unroll
        for (int p = 0; p < 8; ++p) s += ksP[((size_t)bh * 8 + p) * 64 + t];
        ksum[bh * 64 + t] = s;
    }
}

// ---------------------------------------------------------------------------
// K3: apply + output GEMM, per (b, s-tile of 64):
//     denom (all heads, one parallel phase), numerator MFMA per head writing
//     O in-place into the phiQ LDS buffer (disjoint columns), then
//     out = Wo @ O^T + bo  (fp32 coalesced stores).
// ---------------------------------------------------------------------------
__global__ __launch_bounds__(256, 1) void k_apply(const bf16* __restrict__ phiQ,
                                                  const bf16* __restrict__ Wb,
                                                  const bf16* __restrict__ KVT,
                                                  const float* __restrict__ ksum,
                                                  const float* __restrict__ bo,
                                                  float* __restrict__ out) {
    int bid = blockIdx.x;            // b*16 + st
    int st = bid & 15, b = bid >> 4;
    int t = threadIdx.x, lane = t & 63, w = t >> 6, l15 = lane & 15, g = lane >> 4;

    __shared__ bf16 pq[64][520];     // phiQ tile, later reused per-head as O
    __shared__ float ksl[512];
    __shared__ float rden[64][8];
    __shared__ float bol[512];

    {
        int sr = t >> 2;
        const bf16* src = phiQ + ((size_t)b * Sn + st * 64 + sr) * Cn;
#pragma unroll
        for (int it = 0; it < 16; ++it) {
            int c0 = (t & 3) * 8 + it * 32;
            *(bf16x8*)&pq[sr][c0] = *(const bf16x8*)(src + c0);
        }
        ksl[t] = ksum[b * 512 + t];
        ksl[t + 256] = ksum[b * 512 + t + 256];
        bol[t] = bo[t];
        bol[t + 256] = bo[t + 256];
    }
    __syncthreads();
    // denominators: 512 jobs (s,h), 2 per thread
#pragma unroll
    for (int rep = 0; rep < 2; ++rep) {
        int j = rep * 256 + t;
        int s = j & 63, h = j >> 6;
        float acc = 0.f;
#pragma unroll
        for (int dt = 0; dt < 8; ++dt) {
            bf16x8 v = *(const bf16x8*)&pq[s][h * 64 + dt * 8];
#pragma unroll
            for (int i = 0; i < 8; ++i) acc += ksl[h * 64 + dt * 8 + i] * (float)v[i];
        }
        rden[s][h] = 1.f / (acc + 1e-6f);
    }
    __syncthreads();
    // numerator per head; O overwrites pq columns of that head
    for (int h = 0; h < 8; ++h) {
        const bf16* kvb = KVT + ((size_t)(b * 8 + h)) * 4096 + (w * 16 + l15) * 64;
        f32x4 accN[4];
#pragma unroll
        for (int n = 0; n < 4; ++n) accN[n] = (f32x4){0.f,0.f,0.f,0.f};
#pragma unroll
        for (int k2 = 0; k2 < 2; ++k2) {
            bf16x8 afrag = *(const bf16x8*)(kvb + k2 * 32 + g * 8);
#pragma unroll
            for (int n = 0; n < 4; ++n) {
                bf16x8 bfrag = *(const bf16x8*)&pq[n * 16 + l15][h * 64 + k2 * 32 + g * 8];
                accN[n] = MFMA16(afrag, bfrag, accN[n]);
            }
        }
        __syncthreads();             // all reads of pq cols h done before overwrite
#pragma unroll
        for (int n = 0; n < 4; ++n) {
            float rd = rden[n * 16 + l15][h];
            bf16x4 ov;
#pragma unroll
            for (int r = 0; r < 4; ++r) ov[r] = (bf16)(accN[n][r] * rd);
            *(bf16x4*)&pq[n * 16 + l15][h * 64 + w * 16 + g * 4] = ov;
        }
    }
    __syncthreads();
    // out = Wo @ O^T + bo
    const bf16* Wob = Wb + 786432;
    for (int mt = 0; mt < 8; ++mt) {
        int m0 = w * 128 + mt * 16;
        const bf16* wrow = Wob + (size_t)(m0 + l15) * 512;
        f32x4 acc[4];
#pragma unroll
        for (int n = 0; n < 4; ++n) acc[n] = (f32x4){0.f,0.f,0.f,0.f};
#pragma unroll
        for (int k = 0; k < 16; ++k) {
            bf16x8 afrag = *(const bf16x8*)(wrow + k * 32 + g * 8);
#pragma unroll
            for (int n = 0; n < 4; ++n) {
                bf16x8 bfrag = *(const bf16x8*)&pq[n * 16 + l15][k * 32 + g * 8];
                acc[n] = MFMA16(afrag, bfrag, acc[n]);
            }
        }
#pragma unroll
        for (int r = 0; r < 4; ++r) {
            int co = m0 + g * 4 + r;
            float bb = bol[co];
#pragma unroll
            for (int n = 0; n < 4; ++n)
                out[((size_t)b * Cn + co) * Sn + st * 64 + n * 16 + l15] = acc[n][r] + bb;
        }
    }
}

// ---------------------------------------------------------------------------
extern "C" void kernel_launch(void* const* d_in, const int* in_sizes, int n_in,
                              void* d_out, int out_size, void* d_ws, size_t ws_size,
                              hipStream_t stream) {
    const float* x  = (const float*)d_in[0];
    const float* Wq = (const float*)d_in[1];
    const float* Wk = (const float*)d_in[2];
    const float* Wv = (const float*)d_in[3];
    const float* Wo = (const float*)d_in[4];
    const float* bo = (const float*)d_in[5];
    float* out = (float*)d_out;

    char* ws = (char*)d_ws;
    bf16*  phiQ = (bf16*)ws;                       // 33,554,432 B
    bf16*  Wb   = (bf16*)(ws + 33554432);          //  2,097,152 B
    float* ksP  = (float*)(ws + 35651584);         //    524,288 B
    bf16*  KVT  = (bf16*)(ws + 36175872);          //  2,097,152 B
    float* ks   = (float*)(ws + 38273024);         //     65,536 B   (total 38.3 MB)

    // KV partials (32 MB) alias d_out: fully written by k_qkv, consumed by
    // k_red, then k_apply overwrites the whole output buffer.
    bf16*  kvP  = (bf16*)d_out;

    k_cvt_w <<< 512,  256, 0, stream>>>(Wq, Wk, Wv, Wo, Wb);
    k_qkv   <<< 256, 1024, 0, stream>>>(x, Wb, phiQ, kvP, ksP);
    k_red   <<< 256,  256, 0, stream>>>(kvP, ksP, KVT, ks);
    k_apply <<< 512,  256, 0, stream>>>(phiQ, Wb, KVT, ks, bo, out);
}

// Round 8
// 119.742 us; speedup vs baseline: 4.6624x; 1.4018x over previous
//
#include <hip/hip_runtime.h>
#include <hip/hip_bf16.h>

typedef __bf16 bf16;
typedef __bf16 bf16x2 __attribute__((ext_vector_type(2)));
typedef __bf16 bf16x4 __attribute__((ext_vector_type(4)));
typedef __bf16 bf16x8 __attribute__((ext_vector_type(8)));
typedef float  f32x4  __attribute__((ext_vector_type(4)));

#define MFMA16(a,b,c) __builtin_amdgcn_mfma_f32_16x16x32_bf16((a),(b),(c),0,0,0)

// Problem constants: B=32, C=E=512, H=W=32 -> S=1024, 8 heads x 64
constexpr int Cn = 512;
constexpr int Sn = 1024;

// ---------------------------------------------------------------------------
// K0: weights fp32 -> bf16, ALL FOUR in MFMA-A-fragment order:
//     WF[((m*32+gr)*16 + kc)*512 + l*8 + i] = W_m[gr*16+(l&15)][kc*32+(l>>4)*8+i]
//     so a wave's A-frag load for one (matrix, row-group, k-chunk) is a single
//     contiguous 1KB block. m: 0=Wq 1=Wk 2=Wv 3=Wo.
// ---------------------------------------------------------------------------
__global__ __launch_bounds__(256) void k_cvt_w(const float* __restrict__ Wq,
                                               const float* __restrict__ Wk,
                                               const float* __restrict__ Wv,
                                               const float* __restrict__ Wo,
                                               bf16* __restrict__ Wb) {
    int tid = blockIdx.x * 256 + threadIdx.x;   // 512 blocks x 256
    int oidx = tid * 8;
    int m  = oidx >> 18;
    int r  = oidx & 262143;
    int gr = r >> 13;
    int kc = (r >> 9) & 15;
    int l  = (r >> 3) & 63;
    const float* s = (m == 0) ? Wq : (m == 1) ? Wk : (m == 2) ? Wv : Wo;
    const float* src = s + (gr * 16 + (l & 15)) * 512 + kc * 32 + (l >> 4) * 8;
    float4 u = ((const float4*)src)[0], v = ((const float4*)src)[1];
    bf16x8 o;
    o[0] = (bf16)u.x; o[1] = (bf16)u.y; o[2] = (bf16)u.z; o[3] = (bf16)u.w;
    o[4] = (bf16)v.x; o[5] = (bf16)v.y; o[6] = (bf16)v.z; o[7] = (bf16)v.w;
    *(bf16x8*)(Wb + oidx) = o;
}

// ---------------------------------------------------------------------------
// K1: fused transpose + QKV GEMM + phi + per-(sub,head) partial KV / ksum.
//     (unchanged from R7)
// ---------------------------------------------------------------------------
__global__ __launch_bounds__(1024, 4) void k_qkv(const float* __restrict__ x,
                                                 const bf16* __restrict__ Wb,
                                                 bf16* __restrict__ phiQ,
                                                 bf16* __restrict__ kvP,
                                                 float* __restrict__ ksP) {
    int bid = blockIdx.x;            // b*8 + st8
    int st8 = bid & 7, b = bid >> 3;
    int t = threadIdx.x, lane = t & 63, w = t >> 6;   // w in 0..15
    int l15 = lane & 15, g = lane >> 4;
    int hq   = w >> 2;               // head-within-round (0..3)
    int quad = w & 3;                // d-quad within head

    __shared__ bf16 xT[64][520];     // 66.5 KB [s][c] full-k tile
    __shared__ bf16 pk[4][64][72];   // 36.9 KB phi(K) [d][s], 4 heads/round
    __shared__ bf16 vv[4][64][72];   // 36.9 KB V      [e][s]
    __shared__ float ksl[512];       //  2.0 KB ksum accumulator [h*64+d]

    if (t < 512) ksl[t] = 0.f;

    int rp = t >> 2;                 // row-pair: c rows 2rp, 2rp+1
    int sq = t & 3;                  // s-quarter (16 s each)

#pragma unroll 1
    for (int sub = 0; sub < 2; ++sub) {
        int srow0 = st8 * 128 + sub * 64;
        // ---- stage: x fp32 [c][s] -> xT bf16 [s][c]; 4 consecutive lanes
        //      read 256B runs of rows 2rp / 2rp+1 (coalesced) ----
        {
            const float* xr = x + ((size_t)b * Cn + 2 * rp) * Sn + srow0 + sq * 16;
            float4 f0[4], f1[4];
#pragma unroll
            for (int j = 0; j < 4; ++j) {
                f0[j] = ((const float4*)xr)[j];
                f1[j] = ((const float4*)(xr + Sn))[j];
            }
#pragma unroll
            for (int j = 0; j < 4; ++j) {
                const float* e0 = (const float*)&f0[j];
                const float* e1 = (const float*)&f1[j];
#pragma unroll
                for (int e = 0; e < 4; ++e) {
                    int s = sq * 16 + j * 4 + e;
                    bf16x2 pr;
                    pr[0] = (bf16)e0[e];
                    pr[1] = (bf16)e1[e];
                    *(bf16x2*)&xT[s][2 * rp] = pr;
                }
            }
        }
        __syncthreads();             // BAR1: xT ready; prev KV reads done

#pragma unroll 1
        for (int rnd = 0; rnd < 2; ++rnd) {
            int h = rnd * 4 + hq;
            int gr = h * 4 + quad;   // 16-row group index (0..31)
            // ---- QKV compute: M=16 rows (h,quad), N=64, full k=512 ----
            f32x4 aQ[4], aK[4], aV[4];
#pragma unroll
            for (int n = 0; n < 4; ++n) {
                aQ[n] = (f32x4){0.f,0.f,0.f,0.f};
                aK[n] = (f32x4){0.f,0.f,0.f,0.f};
                aV[n] = (f32x4){0.f,0.f,0.f,0.f};
            }
            const bf16* wfQ = Wb + ((size_t)(gr) * 16) * 512 + lane * 8;
            const bf16* wfK = wfQ + (size_t)32 * 16 * 512;
            const bf16* wfV = wfQ + (size_t)64 * 16 * 512;
#pragma unroll 2
            for (int kc = 0; kc < 16; ++kc) {
                bf16x8 fq = *(const bf16x8*)(wfQ + kc * 512);
                bf16x8 fk = *(const bf16x8*)(wfK + kc * 512);
                bf16x8 fv = *(const bf16x8*)(wfV + kc * 512);
#pragma unroll
                for (int n = 0; n < 4; ++n) {
                    bf16x8 bf_ = *(const bf16x8*)&xT[n * 16 + l15][kc * 32 + g * 8];
                    aQ[n] = MFMA16(fq, bf_, aQ[n]);
                    aK[n] = MFMA16(fk, bf_, aK[n]);
                    aV[n] = MFMA16(fv, bf_, aV[n]);
                }
            }
            // ---- phi; pk/vv LDS writes; phiQ direct global; ksum ----
            float kspart[4] = {0.f, 0.f, 0.f, 0.f};
#pragma unroll
            for (int n = 0; n < 4; ++n) {
                bf16x4 qv;
#pragma unroll
                for (int r = 0; r < 4; ++r) {
                    float kv_ = aK[n][r];
                    kv_ = kv_ > 0.f ? kv_ + 1.f : __expf(kv_);
                    bf16 kb = (bf16)kv_;
                    kspart[r] += (float)kb;
                    pk[hq][quad * 16 + g * 4 + r][n * 16 + l15] = kb;
                    vv[hq][quad * 16 + g * 4 + r][n * 16 + l15] = (bf16)aV[n][r];
                    float q = aQ[n][r];
                    q = q > 0.f ? q + 1.f : __expf(q);
                    qv[r] = (bf16)q;
                }
                *(bf16x4*)(phiQ + ((size_t)b * Sn + srow0 + n * 16 + l15) * Cn
                           + h * 64 + quad * 16 + g * 4) = qv;
            }
#pragma unroll
            for (int r = 0; r < 4; ++r) {
                float v = kspart[r];
                v += __shfl_xor(v, 1);
                v += __shfl_xor(v, 2);
                v += __shfl_xor(v, 4);
                v += __shfl_xor(v, 8);
                if (l15 == 0) ksl[h * 64 + quad * 16 + g * 4 + r] += v;
            }
            __syncthreads();         // BAR2: pk/vv of this round ready
            // ---- KV partial MFMA: all 16 waves, m = quad of head h ----
            f32x4 kvacc[4];
#pragma unroll
            for (int n = 0; n < 4; ++n) kvacc[n] = (f32x4){0.f,0.f,0.f,0.f};
#pragma unroll
            for (int k2 = 0; k2 < 2; ++k2) {
                bf16x8 af = *(const bf16x8*)&pk[hq][quad * 16 + l15][k2 * 32 + g * 8];
#pragma unroll
                for (int n = 0; n < 4; ++n) {
                    bf16x8 bf_ = *(const bf16x8*)&vv[hq][n * 16 + l15][k2 * 32 + g * 8];
                    kvacc[n] = MFMA16(af, bf_, kvacc[n]);
                }
            }
            // lane-packed coalesced store (k_red un-permutes):
            // value (n,r) of slot (quad*64+lane) = KV[d=quad*16+g*4+r][e=n*16+l15]
            {
                bf16x8 p0, p1;
#pragma unroll
                for (int r = 0; r < 4; ++r) {
                    p0[r]     = (bf16)kvacc[0][r];
                    p0[4 + r] = (bf16)kvacc[1][r];
                    p1[r]     = (bf16)kvacc[2][r];
                    p1[4 + r] = (bf16)kvacc[3][r];
                }
                size_t base = ((size_t)((b * 8 + h) * 16 + st8 * 2 + sub)) * 4096;
                bf16* dst = kvP + base + (size_t)(quad * 64 + lane) * 16;
                *(bf16x8*)(dst)     = p0;
                *(bf16x8*)(dst + 8) = p1;
            }
            __syncthreads();         // BAR3: KV reads done before next round's writes
        }
    }
    // epilogue: partial ksum -> ksP
    if (t < 512) {
        int h = t >> 6, d = t & 63;
        ksP[((b * 8 + h) * 8 + st8) * 64 + d] = ksl[t];
    }
}

// ---------------------------------------------------------------------------
// K2: reduce lane-packed partials -> KVT[bh][e][d] bf16, ksum[bh][d] fp32.
//     (unchanged from R7)
// ---------------------------------------------------------------------------
__global__ __launch_bounds__(256) void k_red(const bf16* __restrict__ kvP,
                                             const float* __restrict__ ksP,
                                             bf16* __restrict__ KVT,
                                             float* __restrict__ ksum) {
    int bh = blockIdx.x;
    int t = threadIdx.x;             // slot
    int wq = t >> 6, lane = t & 63, g = lane >> 4, l15 = lane & 15;
    float acc[16];
#pragma unroll
    for (int i = 0; i < 16; ++i) acc[i] = 0.f;
#pragma unroll
    for (int p = 0; p < 16; ++p) {
        const bf16* src = kvP + ((size_t)bh * 16 + p) * 4096 + (size_t)t * 16;
        bf16x8 v0 = *(const bf16x8*)(src);
        bf16x8 v1 = *(const bf16x8*)(src + 8);
#pragma unroll
        for (int i = 0; i < 8; ++i) { acc[i] += (float)v0[i]; acc[8 + i] += (float)v1[i]; }
    }
#pragma unroll
    for (int n = 0; n < 4; ++n) {
        bf16x4 o;
#pragma unroll
        for (int r = 0; r < 4; ++r) o[r] = (bf16)acc[n * 4 + r];
        *(bf16x4*)(KVT + (size_t)bh * 4096 + (n * 16 + l15) * 64 + wq * 16 + g * 4) = o;
    }
    if (t < 64) {
        float s = 0.f;
#pragma unroll
        for (int p = 0; p < 8; ++p) s += ksP[((size_t)bh * 8 + p) * 64 + t];
        ksum[bh * 64 + t] = s;
    }
}

// ---------------------------------------------------------------------------
// K3: apply + output GEMM.  grid = (b, st8): 256 blocks x 1024 threads
//     (16 waves, 4/SIMD), 2 s-subs of 64. Per sub:
//       stage phiQ tile -> denom (1024 half-dots + shfl combine) ->
//       numerator (wave = (head, e-half), all heads concurrent, O in regs) ->
//       O*rden written back into pq -> Wo GEMM (wave = 32 out rows, fragged
//       Wo A-frags = contiguous 1KB loads) -> fp32 stores.
// ---------------------------------------------------------------------------
__global__ __launch_bounds__(1024, 4) void k_apply(const bf16* __restrict__ phiQ,
                                                   const bf16* __restrict__ Wb,
                                                   const bf16* __restrict__ KVT,
                                                   const float* __restrict__ ksum,
                                                   const float* __restrict__ bo,
                                                   float* __restrict__ out) {
    int bid = blockIdx.x;            // b*8 + st8
    int st8 = bid & 7, b = bid >> 3;
    int t = threadIdx.x, lane = t & 63, w = t >> 6, l15 = lane & 15, g = lane >> 4;

    __shared__ bf16 pq[64][520];     // 66.5 KB phiQ tile, then O tile
    __shared__ float ksl[512];       //  2 KB
    __shared__ float rden[64][8];    //  2 KB
    __shared__ float bol[512];       //  2 KB

    if (t < 512) {
        ksl[t] = ksum[b * 512 + t];
        bol[t] = bo[t];
    }

#pragma unroll 1
    for (int sub = 0; sub < 2; ++sub) {
        int srow0 = st8 * 128 + sub * 64;
        // ---- stage phiQ tile [64 s][512 c] (coalesced 64B/thread) ----
        {
            int sr = t >> 4, c0 = (t & 15) * 32;
            const bf16* src = phiQ + ((size_t)b * Sn + srow0 + sr) * Cn + c0;
#pragma unroll
            for (int j = 0; j < 4; ++j)
                *(bf16x8*)&pq[sr][c0 + j * 8] = *(const bf16x8*)(src + j * 8);
        }
        __syncthreads();             // BAR1: pq + (ksl,bol on first sub) ready
        // ---- denominators: 512 (s,h) jobs, 2 threads each (32-elem halves) ----
        {
            int j = t >> 1, half = t & 1;
            int s = j & 63, h = j >> 6;
            float acc = 0.f;
#pragma unroll
            for (int dt = 0; dt < 4; ++dt) {
                bf16x8 v = *(const bf16x8*)&pq[s][h * 64 + half * 32 + dt * 8];
#pragma unroll
                for (int i = 0; i < 8; ++i)
                    acc += ksl[h * 64 + half * 32 + dt * 8 + i] * (float)v[i];
            }
            acc += __shfl_xor(acc, 1);
            if (half == 0) rden[s][h] = 1.f / (acc + 1e-6f);
        }
        __syncthreads();             // BAR2: rden ready (pq still phiQ)
        // ---- numerator: wave = (h = w>>1, ehalf = w&1): m = 32 e-rows ----
        int h = w >> 1, eh = w & 1;
        f32x4 accN[2][4];
#pragma unroll
        for (int mi = 0; mi < 2; ++mi)
#pragma unroll
            for (int n = 0; n < 4; ++n) accN[mi][n] = (f32x4){0.f,0.f,0.f,0.f};
        {
            const bf16* kvb = KVT + ((size_t)(b * 8 + h)) * 4096;
#pragma unroll
            for (int k2 = 0; k2 < 2; ++k2) {
#pragma unroll
                for (int mi = 0; mi < 2; ++mi) {
                    bf16x8 af = *(const bf16x8*)(kvb + (eh * 32 + mi * 16 + l15) * 64 + k2 * 32 + g * 8);
#pragma unroll
                    for (int n = 0; n < 4; ++n) {
                        bf16x8 bf_ = *(const bf16x8*)&pq[n * 16 + l15][h * 64 + k2 * 32 + g * 8];
                        accN[mi][n] = MFMA16(af, bf_, accN[mi][n]);
                    }
                }
            }
        }
        __syncthreads();             // BAR3: all numerator reads of pq done
        // ---- O = num * rden overwrites pq (cols h*64+eh*32 .. +32) ----
#pragma unroll
        for (int mi = 0; mi < 2; ++mi)
#pragma unroll
            for (int n = 0; n < 4; ++n) {
                float rd = rden[n * 16 + l15][h];
                bf16x4 ov;
#pragma unroll
                for (int r = 0; r < 4; ++r) ov[r] = (bf16)(accN[mi][n][r] * rd);
                *(bf16x4*)&pq[n * 16 + l15][h * 64 + eh * 32 + mi * 16 + g * 4] = ov;
            }
        __syncthreads();             // BAR4: O tile complete
        // ---- out = Wo @ O^T + bo: wave w owns rows m0..m0+31 ----
        int m0 = w * 32;
        f32x4 acc[2][4];
#pragma unroll
        for (int mi = 0; mi < 2; ++mi)
#pragma unroll
            for (int n = 0; n < 4; ++n) acc[mi][n] = (f32x4){0.f,0.f,0.f,0.f};
        const bf16* WoF = Wb + 786432 + (size_t)(w * 2) * 16 * 512 + lane * 8;
#pragma unroll 2
        for (int kc = 0; kc < 16; ++kc) {
            bf16x8 fa0 = *(const bf16x8*)(WoF + kc * 512);
            bf16x8 fa1 = *(const bf16x8*)(WoF + (16 + kc) * 512);
#pragma unroll
            for (int n = 0; n < 4; ++n) {
                bf16x8 bf_ = *(const bf16x8*)&pq[n * 16 + l15][kc * 32 + g * 8];
                acc[0][n] = MFMA16(fa0, bf_, acc[0][n]);
                acc[1][n] = MFMA16(fa1, bf_, acc[1][n]);
            }
        }
#pragma unroll
        for (int mi = 0; mi < 2; ++mi)
#pragma unroll
            for (int r = 0; r < 4; ++r) {
                int co = m0 + mi * 16 + g * 4 + r;
                float bb = bol[co];
#pragma unroll
                for (int n = 0; n < 4; ++n)
                    out[((size_t)b * Cn + co) * Sn + srow0 + n * 16 + l15] = acc[mi][n][r] + bb;
            }
        __syncthreads();             // BAR5: pq reads done before next sub stage
    }
}

// ---------------------------------------------------------------------------
extern "C" void kernel_launch(void* const* d_in, const int* in_sizes, int n_in,
                              void* d_out, int out_size, void* d_ws, size_t ws_size,
                              hipStream_t stream) {
    const float* x  = (const float*)d_in[0];
    const float* Wq = (const float*)d_in[1];
    const float* Wk = (const float*)d_in[2];
    const float* Wv = (const float*)d_in[3];
    const float* Wo = (const float*)d_in[4];
    const float* bo = (const float*)d_in[5];
    float* out = (float*)d_out;

    char* ws = (char*)d_ws;
    bf16*  phiQ = (bf16*)ws;                       // 33,554,432 B
    bf16*  Wb   = (bf16*)(ws + 33554432);          //  2,097,152 B
    float* ksP  = (float*)(ws + 35651584);         //    524,288 B
    bf16*  KVT  = (bf16*)(ws + 36175872);          //  2,097,152 B
    float* ks   = (float*)(ws + 38273024);         //     65,536 B   (total 38.3 MB)

    // KV partials (32 MB) alias d_out: fully written by k_qkv, consumed by
    // k_red, then k_apply overwrites the whole output buffer.
    bf16*  kvP  = (bf16*)d_out;

    k_cvt_w <<< 512,  256, 0, stream>>>(Wq, Wk, Wv, Wo, Wb);
    k_qkv   <<< 256, 1024, 0, stream>>>(x, Wb, phiQ, kvP, ksP);
    k_red   <<< 256,  256, 0, stream>>>(kvP, ksP, KVT, ks);
    k_apply <<< 256, 1024, 0, stream>>>(phiQ, Wb, KVT, ks, bo, out);
}

// Round 9
// 117.583 us; speedup vs baseline: 4.7480x; 1.0184x over previous
//
#include <hip/hip_runtime.h>
#include <hip/hip_bf16.h>

typedef __bf16 bf16;
typedef __bf16 bf16x2 __attribute__((ext_vector_type(2)));
typedef __bf16 bf16x4 __attribute__((ext_vector_type(4)));
typedef __bf16 bf16x8 __attribute__((ext_vector_type(8)));
typedef float  f32x4  __attribute__((ext_vector_type(4)));

#define MFMA16(a,b,c) __builtin_amdgcn_mfma_f32_16x16x32_bf16((a),(b),(c),0,0,0)

// Problem constants: B=32, C=E=512, H=W=32 -> S=1024, 8 heads x 64
constexpr int Cn = 512;
constexpr int Sn = 1024;

// ---------------------------------------------------------------------------
// K0: weights fp32 -> bf16, ALL FOUR in MFMA-A-fragment order:
//     WF[((m*32+gr)*16 + kc)*512 + l*8 + i] = W_m[gr*16+(l&15)][kc*32+(l>>4)*8+i]
//     so a wave's A-frag load for one (matrix, row-group, k-chunk) is a single
//     contiguous 1KB block. m: 0=Wq 1=Wk 2=Wv 3=Wo.
// ---------------------------------------------------------------------------
__global__ __launch_bounds__(256) void k_cvt_w(const float* __restrict__ Wq,
                                               const float* __restrict__ Wk,
                                               const float* __restrict__ Wv,
                                               const float* __restrict__ Wo,
                                               bf16* __restrict__ Wb) {
    int tid = blockIdx.x * 256 + threadIdx.x;   // 512 blocks x 256
    int oidx = tid * 8;
    int m  = oidx >> 18;
    int r  = oidx & 262143;
    int gr = r >> 13;
    int kc = (r >> 9) & 15;
    int l  = (r >> 3) & 63;
    const float* s = (m == 0) ? Wq : (m == 1) ? Wk : (m == 2) ? Wv : Wo;
    const float* src = s + (gr * 16 + (l & 15)) * 512 + kc * 32 + (l >> 4) * 8;
    float4 u = ((const float4*)src)[0], v = ((const float4*)src)[1];
    bf16x8 o;
    o[0] = (bf16)u.x; o[1] = (bf16)u.y; o[2] = (bf16)u.z; o[3] = (bf16)u.w;
    o[4] = (bf16)v.x; o[5] = (bf16)v.y; o[6] = (bf16)v.z; o[7] = (bf16)v.w;
    *(bf16x8*)(Wb + oidx) = o;
}

// ---------------------------------------------------------------------------
// K1: fused transpose + QKV GEMM + phi + per-(sub,head) partial KV / ksum.
//     R9: kc loop is unroll(1) with explicit depth-1 weight prefetch rotation
//     (load chunk kc+1 while MFMAing chunk kc) + s_setprio around the MFMA
//     cluster. Hides the per-chunk L2 latency inside each wave.
// ---------------------------------------------------------------------------
__global__ __launch_bounds__(1024, 4) void k_qkv(const float* __restrict__ x,
                                                 const bf16* __restrict__ Wb,
                                                 bf16* __restrict__ phiQ,
                                                 bf16* __restrict__ kvP,
                                                 float* __restrict__ ksP) {
    int bid = blockIdx.x;            // b*8 + st8
    int st8 = bid & 7, b = bid >> 3;
    int t = threadIdx.x, lane = t & 63, w = t >> 6;   // w in 0..15
    int l15 = lane & 15, g = lane >> 4;
    int hq   = w >> 2;               // head-within-round (0..3)
    int quad = w & 3;                // d-quad within head

    __shared__ bf16 xT[64][520];     // 66.5 KB [s][c] full-k tile
    __shared__ bf16 pk[4][64][72];   // 36.9 KB phi(K) [d][s], 4 heads/round
    __shared__ bf16 vv[4][64][72];   // 36.9 KB V      [e][s]
    __shared__ float ksl[512];       //  2.0 KB ksum accumulator [h*64+d]

    if (t < 512) ksl[t] = 0.f;

    int rp = t >> 2;                 // row-pair: c rows 2rp, 2rp+1
    int sq = t & 3;                  // s-quarter (16 s each)

#pragma unroll 1
    for (int sub = 0; sub < 2; ++sub) {
        int srow0 = st8 * 128 + sub * 64;
        // ---- stage: x fp32 [c][s] -> xT bf16 [s][c]; 4 consecutive lanes
        //      read 256B runs of rows 2rp / 2rp+1 (coalesced) ----
        {
            const float* xr = x + ((size_t)b * Cn + 2 * rp) * Sn + srow0 + sq * 16;
            float4 f0[4], f1[4];
#pragma unroll
            for (int j = 0; j < 4; ++j) {
                f0[j] = ((const float4*)xr)[j];
                f1[j] = ((const float4*)(xr + Sn))[j];
            }
#pragma unroll
            for (int j = 0; j < 4; ++j) {
                const float* e0 = (const float*)&f0[j];
                const float* e1 = (const float*)&f1[j];
#pragma unroll
                for (int e = 0; e < 4; ++e) {
                    int s = sq * 16 + j * 4 + e;
                    bf16x2 pr;
                    pr[0] = (bf16)e0[e];
                    pr[1] = (bf16)e1[e];
                    *(bf16x2*)&xT[s][2 * rp] = pr;
                }
            }
        }
        __syncthreads();             // BAR1: xT ready; prev KV reads done

#pragma unroll 1
        for (int rnd = 0; rnd < 2; ++rnd) {
            int h = rnd * 4 + hq;
            int gr = h * 4 + quad;   // 16-row group index (0..31)
            // ---- QKV compute: M=16 rows (h,quad), N=64, full k=512 ----
            f32x4 aQ[4], aK[4], aV[4];
#pragma unroll
            for (int n = 0; n < 4; ++n) {
                aQ[n] = (f32x4){0.f,0.f,0.f,0.f};
                aK[n] = (f32x4){0.f,0.f,0.f,0.f};
                aV[n] = (f32x4){0.f,0.f,0.f,0.f};
            }
            const bf16* wfQ = Wb + ((size_t)(gr) * 16) * 512 + lane * 8;
            const bf16* wfK = wfQ + (size_t)32 * 16 * 512;
            const bf16* wfV = wfQ + (size_t)64 * 16 * 512;
            // depth-1 prefetch rotation: load chunk kc+1 while MFMAing kc
            bf16x8 cq = *(const bf16x8*)(wfQ);
            bf16x8 ck = *(const bf16x8*)(wfK);
            bf16x8 cv = *(const bf16x8*)(wfV);
#pragma unroll 1
            for (int kc = 0; kc < 16; ++kc) {
                bf16x8 nq, nk, nv;
                if (kc < 15) {
                    nq = *(const bf16x8*)(wfQ + (kc + 1) * 512);
                    nk = *(const bf16x8*)(wfK + (kc + 1) * 512);
                    nv = *(const bf16x8*)(wfV + (kc + 1) * 512);
                }
                __builtin_amdgcn_s_setprio(1);
#pragma unroll
                for (int n = 0; n < 4; ++n) {
                    bf16x8 bf_ = *(const bf16x8*)&xT[n * 16 + l15][kc * 32 + g * 8];
                    aQ[n] = MFMA16(cq, bf_, aQ[n]);
                    aK[n] = MFMA16(ck, bf_, aK[n]);
                    aV[n] = MFMA16(cv, bf_, aV[n]);
                }
                __builtin_amdgcn_s_setprio(0);
                cq = nq; ck = nk; cv = nv;
            }
            // ---- phi; pk/vv LDS writes; phiQ direct global; ksum ----
            float kspart[4] = {0.f, 0.f, 0.f, 0.f};
#pragma unroll
            for (int n = 0; n < 4; ++n) {
                bf16x4 qv;
#pragma unroll
                for (int r = 0; r < 4; ++r) {
                    float kv_ = aK[n][r];
                    kv_ = kv_ > 0.f ? kv_ + 1.f : __expf(kv_);
                    bf16 kb = (bf16)kv_;
                    kspart[r] += (float)kb;
                    pk[hq][quad * 16 + g * 4 + r][n * 16 + l15] = kb;
                    vv[hq][quad * 16 + g * 4 + r][n * 16 + l15] = (bf16)aV[n][r];
                    float q = aQ[n][r];
                    q = q > 0.f ? q + 1.f : __expf(q);
                    qv[r] = (bf16)q;
                }
                *(bf16x4*)(phiQ + ((size_t)b * Sn + srow0 + n * 16 + l15) * Cn
                           + h * 64 + quad * 16 + g * 4) = qv;
            }
#pragma unroll
            for (int r = 0; r < 4; ++r) {
                float v = kspart[r];
                v += __shfl_xor(v, 1);
                v += __shfl_xor(v, 2);
                v += __shfl_xor(v, 4);
                v += __shfl_xor(v, 8);
                if (l15 == 0) ksl[h * 64 + quad * 16 + g * 4 + r] += v;
            }
            __syncthreads();         // BAR2: pk/vv of this round ready
            // ---- KV partial MFMA: all 16 waves, m = quad of head h ----
            f32x4 kvacc[4];
#pragma unroll
            for (int n = 0; n < 4; ++n) kvacc[n] = (f32x4){0.f,0.f,0.f,0.f};
#pragma unroll
            for (int k2 = 0; k2 < 2; ++k2) {
                bf16x8 af = *(const bf16x8*)&pk[hq][quad * 16 + l15][k2 * 32 + g * 8];
#pragma unroll
                for (int n = 0; n < 4; ++n) {
                    bf16x8 bf_ = *(const bf16x8*)&vv[hq][n * 16 + l15][k2 * 32 + g * 8];
                    kvacc[n] = MFMA16(af, bf_, kvacc[n]);
                }
            }
            // lane-packed coalesced store (k_red un-permutes):
            // value (n,r) of slot (quad*64+lane) = KV[d=quad*16+g*4+r][e=n*16+l15]
            {
                bf16x8 p0, p1;
#pragma unroll
                for (int r = 0; r < 4; ++r) {
                    p0[r]     = (bf16)kvacc[0][r];
                    p0[4 + r] = (bf16)kvacc[1][r];
                    p1[r]     = (bf16)kvacc[2][r];
                    p1[4 + r] = (bf16)kvacc[3][r];
                }
                size_t base = ((size_t)((b * 8 + h) * 16 + st8 * 2 + sub)) * 4096;
                bf16* dst = kvP + base + (size_t)(quad * 64 + lane) * 16;
                *(bf16x8*)(dst)     = p0;
                *(bf16x8*)(dst + 8) = p1;
            }
            __syncthreads();         // BAR3: KV reads done before next round's writes
        }
    }
    // epilogue: partial ksum -> ksP
    if (t < 512) {
        int h = t >> 6, d = t & 63;
        ksP[((b * 8 + h) * 8 + st8) * 64 + d] = ksl[t];
    }
}

// ---------------------------------------------------------------------------
// K2: reduce lane-packed partials -> KVT[bh][e][d] bf16, ksum[bh][d] fp32.
//     (unchanged)
// ---------------------------------------------------------------------------
__global__ __launch_bounds__(256) void k_red(const bf16* __restrict__ kvP,
                                             const float* __restrict__ ksP,
                                             bf16* __restrict__ KVT,
                                             float* __restrict__ ksum) {
    int bh = blockIdx.x;
    int t = threadIdx.x;             // slot
    int wq = t >> 6, lane = t & 63, g = lane >> 4, l15 = lane & 15;
    float acc[16];
#pragma unroll
    for (int i = 0; i < 16; ++i) acc[i] = 0.f;
#pragma unroll
    for (int p = 0; p < 16; ++p) {
        const bf16* src = kvP + ((size_t)bh * 16 + p) * 4096 + (size_t)t * 16;
        bf16x8 v0 = *(const bf16x8*)(src);
        bf16x8 v1 = *(const bf16x8*)(src + 8);
#pragma unroll
        for (int i = 0; i < 8; ++i) { acc[i] += (float)v0[i]; acc[8 + i] += (float)v1[i]; }
    }
#pragma unroll
    for (int n = 0; n < 4; ++n) {
        bf16x4 o;
#pragma unroll
        for (int r = 0; r < 4; ++r) o[r] = (bf16)acc[n * 4 + r];
        *(bf16x4*)(KVT + (size_t)bh * 4096 + (n * 16 + l15) * 64 + wq * 16 + g * 4) = o;
    }
    if (t < 64) {
        float s = 0.f;
#pragma unroll
        for (int p = 0; p < 8; ++p) s += ksP[((size_t)bh * 8 + p) * 64 + t];
        ksum[bh * 64 + t] = s;
    }
}

// ---------------------------------------------------------------------------
// K3: apply + output GEMM (unchanged from R8).
// ---------------------------------------------------------------------------
__global__ __launch_bounds__(1024, 4) void k_apply(const bf16* __restrict__ phiQ,
                                                   const bf16* __restrict__ Wb,
                                                   const bf16* __restrict__ KVT,
                                                   const float* __restrict__ ksum,
                                                   const float* __restrict__ bo,
                                                   float* __restrict__ out) {
    int bid = blockIdx.x;            // b*8 + st8
    int st8 = bid & 7, b = bid >> 3;
    int t = threadIdx.x, lane = t & 63, w = t >> 6, l15 = lane & 15, g = lane >> 4;

    __shared__ bf16 pq[64][520];     // 66.5 KB phiQ tile, then O tile
    __shared__ float ksl[512];       //  2 KB
    __shared__ float rden[64][8];    //  2 KB
    __shared__ float bol[512];       //  2 KB

    if (t < 512) {
        ksl[t] = ksum[b * 512 + t];
        bol[t] = bo[t];
    }

#pragma unroll 1
    for (int sub = 0; sub < 2; ++sub) {
        int srow0 = st8 * 128 + sub * 64;
        // ---- stage phiQ tile [64 s][512 c] (coalesced 64B/thread) ----
        {
            int sr = t >> 4, c0 = (t & 15) * 32;
            const bf16* src = phiQ + ((size_t)b * Sn + srow0 + sr) * Cn + c0;
#pragma unroll
            for (int j = 0; j < 4; ++j)
                *(bf16x8*)&pq[sr][c0 + j * 8] = *(const bf16x8*)(src + j * 8);
        }
        __syncthreads();             // BAR1: pq + (ksl,bol on first sub) ready
        // ---- denominators: 512 (s,h) jobs, 2 threads each (32-elem halves) ----
        {
            int j = t >> 1, half = t & 1;
            int s = j & 63, h = j >> 6;
            float acc = 0.f;
#pragma unroll
            for (int dt = 0; dt < 4; ++dt) {
                bf16x8 v = *(const bf16x8*)&pq[s][h * 64 + half * 32 + dt * 8];
#pragma unroll
                for (int i = 0; i < 8; ++i)
                    acc += ksl[h * 64 + half * 32 + dt * 8 + i] * (float)v[i];
            }
            acc += __shfl_xor(acc, 1);
            if (half == 0) rden[s][h] = 1.f / (acc + 1e-6f);
        }
        __syncthreads();             // BAR2: rden ready (pq still phiQ)
        // ---- numerator: wave = (h = w>>1, ehalf = w&1): m = 32 e-rows ----
        int h = w >> 1, eh = w & 1;
        f32x4 accN[2][4];
#pragma unroll
        for (int mi = 0; mi < 2; ++mi)
#pragma unroll
            for (int n = 0; n < 4; ++n) accN[mi][n] = (f32x4){0.f,0.f,0.f,0.f};
        {
            const bf16* kvb = KVT + ((size_t)(b * 8 + h)) * 4096;
#pragma unroll
            for (int k2 = 0; k2 < 2; ++k2) {
#pragma unroll
                for (int mi = 0; mi < 2; ++mi) {
                    bf16x8 af = *(const bf16x8*)(kvb + (eh * 32 + mi * 16 + l15) * 64 + k2 * 32 + g * 8);
#pragma unroll
                    for (int n = 0; n < 4; ++n) {
                        bf16x8 bf_ = *(const bf16x8*)&pq[n * 16 + l15][h * 64 + k2 * 32 + g * 8];
                        accN[mi][n] = MFMA16(af, bf_, accN[mi][n]);
                    }
                }
            }
        }
        __syncthreads();             // BAR3: all numerator reads of pq done
        // ---- O = num * rden overwrites pq (cols h*64+eh*32 .. +32) ----
#pragma unroll
        for (int mi = 0; mi < 2; ++mi)
#pragma unroll
            for (int n = 0; n < 4; ++n) {
                float rd = rden[n * 16 + l15][h];
                bf16x4 ov;
#pragma unroll
                for (int r = 0; r < 4; ++r) ov[r] = (bf16)(accN[mi][n][r] * rd);
                *(bf16x4*)&pq[n * 16 + l15][h * 64 + eh * 32 + mi * 16 + g * 4] = ov;
            }
        __syncthreads();             // BAR4: O tile complete
        // ---- out = Wo @ O^T + bo: wave w owns rows m0..m0+31 ----
        int m0 = w * 32;
        f32x4 acc[2][4];
#pragma unroll
        for (int mi = 0; mi < 2; ++mi)
#pragma unroll
            for (int n = 0; n < 4; ++n) acc[mi][n] = (f32x4){0.f,0.f,0.f,0.f};
        const bf16* WoF = Wb + 786432 + (size_t)(w * 2) * 16 * 512 + lane * 8;
#pragma unroll 2
        for (int kc = 0; kc < 16; ++kc) {
            bf16x8 fa0 = *(const bf16x8*)(WoF + kc * 512);
            bf16x8 fa1 = *(const bf16x8*)(WoF + (16 + kc) * 512);
#pragma unroll
            for (int n = 0; n < 4; ++n) {
                bf16x8 bf_ = *(const bf16x8*)&pq[n * 16 + l15][kc * 32 + g * 8];
                acc[0][n] = MFMA16(fa0, bf_, acc[0][n]);
                acc[1][n] = MFMA16(fa1, bf_, acc[1][n]);
            }
        }
#pragma unroll
        for (int mi = 0; mi < 2; ++mi)
#pragma unroll
            for (int r = 0; r < 4; ++r) {
                int co = m0 + mi * 16 + g * 4 + r;
                float bb = bol[co];
#pragma unroll
                for (int n = 0; n < 4; ++n)
                    out[((size_t)b * Cn + co) * Sn + srow0 + n * 16 + l15] = acc[mi][n][r] + bb;
            }
        __syncthreads();             // BAR5: pq reads done before next sub stage
    }
}

// ---------------------------------------------------------------------------
extern "C" void kernel_launch(void* const* d_in, const int* in_sizes, int n_in,
                              void* d_out, int out_size, void* d_ws, size_t ws_size,
                              hipStream_t stream) {
    const float* x  = (const float*)d_in[0];
    const float* Wq = (const float*)d_in[1];
    const float* Wk = (const float*)d_in[2];
    const float* Wv = (const float*)d_in[3];
    const float* Wo = (const float*)d_in[4];
    const float* bo = (const float*)d_in[5];
    float* out = (float*)d_out;

    char* ws = (char*)d_ws;
    bf16*  phiQ = (bf16*)ws;                       // 33,554,432 B
    bf16*  Wb   = (bf16*)(ws + 33554432);          //  2,097,152 B
    float* ksP  = (float*)(ws + 35651584);         //    524,288 B
    bf16*  KVT  = (bf16*)(ws + 36175872);          //  2,097,152 B
    float* ks   = (float*)(ws + 38273024);         //     65,536 B   (total 38.3 MB)

    // KV partials (32 MB) alias d_out: fully written by k_qkv, consumed by
    // k_red, then k_apply overwrites the whole output buffer.
    bf16*  kvP  = (bf16*)d_out;

    k_cvt_w <<< 512,  256, 0, stream>>>(Wq, Wk, Wv, Wo, Wb);
    k_qkv   <<< 256, 1024, 0, stream>>>(x, Wb, phiQ, kvP, ksP);
    k_red   <<< 256,  256, 0, stream>>>(kvP, ksP, KVT, ks);
    k_apply <<< 256, 1024, 0, stream>>>(phiQ, Wb, KVT, ks, bo, out);
}